// Round 10
// baseline (1130.424 us; speedup 1.0000x reference)
//
#include <hip/hip_runtime.h>
#include <hip/hip_bf16.h>
#include <math.h>

// ---------------------------------------------------------------------------
// GINE model: 3x (GINEConv + BN + ReLU) -> global mean pool -> MLP -> sigmoid
// Round 10: edge kernel segment-sum via per-wave LDS ds_add_f32 (replaces the
// O(nseg*16) predicated VALU scan), multi-block scan for the CSR build.
// ---------------------------------------------------------------------------

typedef __attribute__((ext_vector_type(8))) short short8v;
typedef __attribute__((ext_vector_type(4))) float f32x4;
typedef __attribute__((ext_vector_type(4))) unsigned short us4;
typedef __attribute__((ext_vector_type(8))) unsigned short us8;

static __device__ __forceinline__ float bf2f(unsigned short u) {
    union { unsigned int u32; float f; } c; c.u32 = ((unsigned int)u) << 16; return c.f;
}
static __device__ __forceinline__ unsigned short f2bf(float f) {
    union { float f; unsigned int u; } c; c.f = f;
    unsigned int lsb = (c.u >> 16) & 1u;
    c.u += 0x7fffu + lsb;
    return (unsigned short)(c.u >> 16);
}

__global__ void k_zero_i(int* __restrict__ p, int n) {
    int i = blockIdx.x * blockDim.x + threadIdx.x;
    int st = gridDim.x * blockDim.x;
    for (; i < n; i += st) p[i] = 0;
}

// dst histogram (blocks 0..511) + batch histogram (blocks 512..639)
__global__ void k_hist2(const int* __restrict__ dst, int E,
                        const int* __restrict__ batch, int N,
                        int* __restrict__ ideg, int* __restrict__ gcnt) {
    int b = blockIdx.x;
    if (b < 512) {
        int i = b * 256 + threadIdx.x, st = 512 * 256;
        for (; i < E; i += st) atomicAdd(&ideg[dst[i]], 1);
    } else {
        int i = (b - 512) * 256 + threadIdx.x, st = 128 * 256;
        for (; i < N; i += st) atomicAdd(&gcnt[batch[i]], 1);
    }
}

// ---- multi-block scan: part -> mid -> out ----
__global__ __launch_bounds__(256) void k_scan_part(const int* __restrict__ in,
                                                   int* __restrict__ part, int n) {
    __shared__ int wtot[4];
    const int tid = threadIdx.x, lane = tid & 63, wv = tid >> 6;
    int i = blockIdx.x * 256 + tid;
    int s = (i < n) ? in[i] : 0;
#pragma unroll
    for (int off = 1; off < 64; off <<= 1) s += __shfl_xor(s, off);
    if (lane == 0) wtot[wv] = s;
    __syncthreads();
    if (tid == 0) part[blockIdx.x] = wtot[0] + wtot[1] + wtot[2] + wtot[3];
}

// single-block two-level exclusive scan helper (C = elems per thread)
static __device__ void scan_block(const int* __restrict__ in, int* __restrict__ out,
                                  int n, int* wsum) {
    const int tid = threadIdx.x;
    const int lane = tid & 63, wv = tid >> 6;
    const int C = (n + 1023) >> 10;
    const int base = tid * C;
    int s = 0;
    for (int k = 0; k < C; ++k) {
        int i = base + k;
        if (i < n) s += in[i];
    }
    int incl = s;
#pragma unroll
    for (int off = 1; off < 64; off <<= 1) {
        int t = __shfl_up(incl, off);
        if (lane >= off) incl += t;
    }
    if (lane == 63) wsum[wv] = incl;
    __syncthreads();
    int woff = 0;
    for (int i2 = 0; i2 < wv; ++i2) woff += wsum[i2];
    int run = woff + incl - s;
    for (int k = 0; k < C; ++k) {
        int i = base + k;
        if (i < n) {
            out[i] = run;
            run += in[i];
        }
    }
    if (tid == 1023) out[n] = run;
    __syncthreads();
}

// scan the block partials (-> part_s) + full gptr scan; write rowptr[N]=total
__global__ __launch_bounds__(1024) void k_scan_mid(
    const int* __restrict__ part, int* __restrict__ part_s, int npart,
    const int* __restrict__ gcnt, int* __restrict__ gptr, int G,
    int* __restrict__ rowptr, int N) {
    __shared__ int wsum[16];
    scan_block(part, part_s, npart, wsum);
    if (threadIdx.x == 0) rowptr[N] = part_s[npart];
    scan_block(gcnt, gptr, G, wsum);
}

__global__ __launch_bounds__(256) void k_scan_out(const int* __restrict__ in,
                                                  const int* __restrict__ part_s,
                                                  int* __restrict__ rowptr,
                                                  int* __restrict__ cursor, int n) {
    __shared__ int wtot[4];
    const int tid = threadIdx.x, lane = tid & 63, wv = tid >> 6;
    int i = blockIdx.x * 256 + tid;
    int v = (i < n) ? in[i] : 0;
    int s = v;
#pragma unroll
    for (int off = 1; off < 64; off <<= 1) {
        int t = __shfl_up(s, off);
        if (lane >= off) s += t;
    }
    if (lane == 63) wtot[wv] = s;
    __syncthreads();
    int woff = 0;
    for (int k = 0; k < wv; ++k) woff += wtot[k];
    int excl = part_s[blockIdx.x] + woff + s - v;
    if (i < n) { rowptr[i] = excl; cursor[i] = excl; }
}

// bucket edges by dst + pad tail [E, Epad)
__global__ void k_scatter(const int* __restrict__ ei, int E, int Epad,
                          int* __restrict__ cursor, int* __restrict__ eid_s,
                          int* __restrict__ esrc_s, int* __restrict__ dst_s,
                          unsigned short* __restrict__ ea_s) {
    int i = blockIdx.x * blockDim.x + threadIdx.x;
    int st = gridDim.x * blockDim.x;
    for (int k = i; k < E; k += st) {
        int d = ei[E + k];
        int pos = atomicAdd(&cursor[d], 1);
        eid_s[pos] = k;
        esrc_s[pos] = ei[k];
        dst_s[pos] = d;
    }
    if (i < Epad - E) {
        esrc_s[E + i] = 0;
        dst_s[E + i] = -1;
        us4 z = {0, 0, 0, 0};
        us4* p = (us4*)(ea_s + (size_t)(E + i) * 32);
#pragma unroll
        for (int q = 0; q < 8; ++q) p[q] = z;
    }
}

// ea_s[pos] = bf16(ea[eid_s[pos]]), CSR order
__global__ void k_permute_ea(const float* __restrict__ ea, const int* __restrict__ eid_s,
                             unsigned short* __restrict__ ea_s, int E) {
    int i = blockIdx.x * blockDim.x + threadIdx.x;
    int st = gridDim.x * blockDim.x;
    const int ng = E * 4;
    for (; i < ng; i += st) {
        int pos = i >> 2, q = i & 3;
        int e = eid_s[pos];
        const float4* sp = (const float4*)(ea + (size_t)e * 32 + q * 8);
        float4 a = sp[0], b = sp[1];
        us4 o0, o1;
        o0.x = f2bf(a.x); o0.y = f2bf(a.y); o0.z = f2bf(a.z); o0.w = f2bf(a.w);
        o1.x = f2bf(b.x); o1.y = f2bf(b.y); o1.z = f2bf(b.z); o1.w = f2bf(b.w);
        us4* dp = (us4*)(ea_s + (size_t)pos * 32 + q * 8);
        dp[0] = o0; dp[1] = o1;
    }
}

// weight prep: bf16 casts of we1/2/3, wn1/2/3 + w4 transpose with permuted rows
__global__ void k_wprep(const float* __restrict__ we1, const float* __restrict__ we2,
                        const float* __restrict__ we3, const float* __restrict__ wn1,
                        const float* __restrict__ wn2, const float* __restrict__ wn3,
                        const float* __restrict__ w4,
                        unsigned short* __restrict__ webf1, unsigned short* __restrict__ webf2,
                        unsigned short* __restrict__ webf3, unsigned short* __restrict__ wnbf1,
                        unsigned short* __restrict__ wnbf2, unsigned short* __restrict__ wnbf3,
                        float* __restrict__ w4t) {
    int idx = blockIdx.x * blockDim.x + threadIdx.x;
    const float* s; unsigned short* d; int rel;
    if (idx < 512)        { s = we1; d = webf1; rel = idx; }
    else if (idx < 2560)  { s = we2; d = webf2; rel = idx - 512; }
    else if (idx < 4608)  { s = we3; d = webf3; rel = idx - 2560; }
    else if (idx < 8704)  { s = wn1; d = wnbf1; rel = idx - 4608; }
    else if (idx < 25088) { s = wn2; d = wnbf2; rel = idx - 8704; }
    else if (idx < 41472) { s = wn3; d = wnbf3; rel = idx - 25088; }
    else if (idx < 49664) {
        int rel2 = idx - 41472;
        int k = rel2 >> 5;                 // position 0..255 in permuted pooled vec
        int j0 = (rel2 & 31) * 4;
        int ck = (k & 0xC0) | (((k & 3) * 16) + ((k & 63) >> 2));
        float4 o;
        o.x = w4[(j0 + 0) * 256 + ck]; o.y = w4[(j0 + 1) * 256 + ck];
        o.z = w4[(j0 + 2) * 256 + ck]; o.w = w4[(j0 + 3) * 256 + ck];
        *(float4*)(w4t + k * 128 + j0) = o;
        return;
    } else return;
    float4 t = ((const float4*)s)[rel];
    us4 o; o.x = f2bf(t.x); o.y = f2bf(t.y); o.z = f2bf(t.z); o.w = f2bf(t.w);
    ((us4*)d)[rel] = o;
}

// x -> permuted bf16 x_bf + natural f32 self-term init
__global__ void k_xprep(const float* __restrict__ x, unsigned short* __restrict__ x_bf,
                        float* __restrict__ aggrA, int n16) {
    int i = blockIdx.x * blockDim.x + threadIdx.x;
    int st = gridDim.x * blockDim.x;
    for (; i < n16; i += st) {
        int n = i >> 4, j = i & 15;
        float4 t = *(const float4*)(x + (size_t)n * 64 + j * 4);
        ((float4*)aggrA)[i] = t;
        us4 o;
        o.x = f2bf(x[(size_t)n * 64 + j]);
        o.y = f2bf(x[(size_t)n * 64 + 16 + j]);
        o.z = f2bf(x[(size_t)n * 64 + 32 + j]);
        o.w = f2bf(x[(size_t)n * 64 + 48 + j]);
        *(us4*)(x_bf + (size_t)n * 64 + j * 4) = o;
    }
}

// ---------------------------------------------------------------------------
// Edge kernel. 1 tile (64 edges) per wave; 64-col slice per wave (D=256: 4
// waves/block share the tile; D=64: each wave owns its tile). Permuted-h 8B
// gathers; segment sum via per-wave LDS ds_add_f32 (fallback to predicated
// loop if nseg>32); contiguous-64B global atomic flush on natural aggr.
// ---------------------------------------------------------------------------
template<int D>
__global__ __launch_bounds__(256) void k_edge_mfma(
    const unsigned short* __restrict__ hbf,   // [N][D] bf16, PERMUTED layout
    const unsigned short* __restrict__ ea_s,  // [Epad][32] bf16, CSR order
    const int* __restrict__ esrc_s,           // [Epad]
    const int* __restrict__ dst_s,            // [Epad]
    const unsigned short* __restrict__ webf,  // [D][32] bf16, natural rows
    const float* __restrict__ be,             // [D]
    float* __restrict__ aggr,                 // [N][D] f32, natural layout
    int E)
{
    __shared__ float segbuf[4][32][64];
    const int tid = threadIdx.x;
    const int lane = tid & 63;
    const int w = tid >> 6;
    const int l15 = lane & 15;
    const int lhi = lane >> 4;

    const int wavetile = (D == 256) ? (int)blockIdx.x : ((int)blockIdx.x * 4 + w);
    const int colbase  = (D == 256) ? (w * 64) : 0;
    const int e0 = wavetile * 64;
    if (e0 >= E) return;

    const int dstreg = dst_s[e0 + lane];

    int4 src4[4];
#pragma unroll
    for (int q = 0; q < 4; ++q)
        src4[q] = *(const int4*)(esrc_s + e0 + q * 16 + lhi * 4);

    short8v afr[4];
#pragma unroll
    for (int q = 0; q < 4; ++q)
        afr[q] = *(const short8v*)(ea_s + (size_t)(e0 + q * 16 + l15) * 32 + lhi * 8);

    short8v bfr[4]; float bias[4];
#pragma unroll
    for (int t = 0; t < 4; ++t) {
        int c = colbase + t * 16 + l15;
        bfr[t] = *(const short8v*)(webf + (size_t)c * 32 + lhi * 8);
        bias[t] = be[c];
    }

    // permuted h-gather: one us4 per fragment row -> channels {t*16+l15}
    us4 hv[4][4];
#pragma unroll
    for (int q = 0; q < 4; ++q) {
        const int sr[4] = {src4[q].x, src4[q].y, src4[q].z, src4[q].w};
#pragma unroll
        for (int i = 0; i < 4; ++i)
            hv[q][i] = *(const us4*)(hbf + (size_t)sr[i] * D + colbase + l15 * 4);
    }

    f32x4 acc[4][4];
#pragma unroll
    for (int q = 0; q < 4; ++q)
#pragma unroll
        for (int t = 0; t < 4; ++t) {
            f32x4 ci; ci[0] = bias[t]; ci[1] = bias[t]; ci[2] = bias[t]; ci[3] = bias[t];
            acc[q][t] = __builtin_amdgcn_mfma_f32_16x16x32_bf16(afr[q], bfr[t], ci, 0, 0, 0);
        }

    // m = relu(el + h_src)
#pragma unroll
    for (int q = 0; q < 4; ++q)
#pragma unroll
        for (int i = 0; i < 4; ++i) {
            us4 h4 = hv[q][i];
#pragma unroll
            for (int t = 0; t < 4; ++t)
                acc[q][t][i] = fmaxf(acc[q][t][i] + bf2f(h4[t]), 0.0f);
        }

    // segment structure over sorted dst (wave-uniform)
    int dprev = __shfl_up(dstreg, 1);
    bool bflag = (lane > 0) && (dstreg != dprev);
    unsigned long long bmask = __ballot(bflag);
    const int nseg = __builtin_popcountll(bmask) + 1;
    unsigned mlo = (unsigned)bmask, mhi = (unsigned)(bmask >> 32);
    const int segid_lane =
        __builtin_amdgcn_mbcnt_hi(mhi, __builtin_amdgcn_mbcnt_lo(mlo, 0)) + (bflag ? 1 : 0);

    int segid_qi[4][4];
#pragma unroll
    for (int q = 0; q < 4; ++q)
#pragma unroll
        for (int i = 0; i < 4; ++i) {
            int row = q * 16 + lhi * 4 + i;
            unsigned long long p = 1ull << row;
            segid_qi[q][i] = __builtin_popcountll(bmask & (p | (p - 1ull)));
        }

    if (nseg <= 32) {
        // zero the live rows of this wave's seg buffer
        for (int s = 0; s < nseg; ++s) segbuf[w][s][lane] = 0.0f;
        // LDS segmented reduction: 64 ds_add_f32 per lane
#pragma unroll
        for (int q = 0; q < 4; ++q)
#pragma unroll
            for (int i = 0; i < 4; ++i) {
                int sid = segid_qi[q][i];
#pragma unroll
                for (int t = 0; t < 4; ++t)
                    atomicAdd(&segbuf[w][sid][t * 16 + l15], acc[q][t][i]);
            }
        // flush: lane covers one col; contiguous 256B atomics per segment
        for (int s = 0; s < nseg; ++s) {
            unsigned long long ms = __ballot(segid_lane == s);
            int fl = (int)__builtin_ctzll(ms);
            int dseg = __shfl(dstreg, fl);
            float v = segbuf[w][s][lane];
            if (dseg >= 0)
                atomicAdd(aggr + (size_t)dseg * D + colbase + lane, v);
        }
    } else {
        // fallback: predicated per-segment scan (rare)
        for (int s = 0; s < nseg; ++s) {
            float a[4] = {0.0f, 0.0f, 0.0f, 0.0f};
#pragma unroll
            for (int q = 0; q < 4; ++q)
#pragma unroll
                for (int i = 0; i < 4; ++i) {
                    bool tk = (segid_qi[q][i] == s);
#pragma unroll
                    for (int t = 0; t < 4; ++t) a[t] += tk ? acc[q][t][i] : 0.0f;
                }
#pragma unroll
            for (int t = 0; t < 4; ++t) {
                a[t] += __shfl_xor(a[t], 16);
                a[t] += __shfl_xor(a[t], 32);
            }
            unsigned long long ms = __ballot(segid_lane == s);
            int fl = (int)__builtin_ctzll(ms);
            int dseg = __shfl(dstreg, fl);
            if (dseg >= 0 && lhi == 0) {
#pragma unroll
                for (int t = 0; t < 4; ++t)
                    atomicAdd(aggr + (size_t)dseg * D + colbase + t * 16 + l15, a[t]);
            }
        }
    }
}

// ---------------------------------------------------------------------------
// MFMA node GEMM + BN + ReLU. Natural aggr in/out; h_bf stored PERMUTED via
// two 16B stores per row-fragment.
// ---------------------------------------------------------------------------
template<int K, bool AW>
__global__ __launch_bounds__(256) void k_node_mfma(
    const float* __restrict__ A, const unsigned short* __restrict__ wnbf,
    const float* __restrict__ bnb, const float* __restrict__ g,
    const float* __restrict__ b, const float* __restrict__ rm,
    const float* __restrict__ rv, unsigned short* __restrict__ out,
    float* __restrict__ aggr_out, int N)
{
    const int tid = threadIdx.x;
    const int lane = tid & 63;
    const int w = tid >> 6;
    const int l15 = lane & 15;
    const int lhi = lane >> 4;
    const int row0 = blockIdx.x * 64;
    const int ncol0 = w * 64;

    f32x4 scale[4], shift[4];
    f32x4 acc[4][4];
#pragma unroll
    for (int q = 0; q < 4; ++q) {
        int n0 = ncol0 + q * 16 + lhi * 4;
        float4 gg = *(const float4*)(g + n0);
        float4 rvv = *(const float4*)(rv + n0);
        float4 bb = *(const float4*)(b + n0);
        float4 rmm = *(const float4*)(rm + n0);
        float4 bn = *(const float4*)(bnb + n0);
        f32x4 sc, sh, ci;
        sc[0] = gg.x * rsqrtf(rvv.x + 1e-5f);
        sc[1] = gg.y * rsqrtf(rvv.y + 1e-5f);
        sc[2] = gg.z * rsqrtf(rvv.z + 1e-5f);
        sc[3] = gg.w * rsqrtf(rvv.w + 1e-5f);
        sh[0] = bb.x - rmm.x * sc[0];
        sh[1] = bb.y - rmm.y * sc[1];
        sh[2] = bb.z - rmm.z * sc[2];
        sh[3] = bb.w - rmm.w * sc[3];
        ci[0] = bn.x; ci[1] = bn.y; ci[2] = bn.z; ci[3] = bn.w;
        scale[q] = sc; shift[q] = sh;
#pragma unroll
        for (int r = 0; r < 4; ++r) acc[q][r] = ci;
    }

    for (int k0 = 0; k0 < K; k0 += 32) {
        short8v wfr[4];
#pragma unroll
        for (int q = 0; q < 4; ++q)
            wfr[q] = *(const short8v*)(wnbf + (size_t)(ncol0 + q * 16 + l15) * K + k0 + lhi * 8);
        short8v afr[4];
#pragma unroll
        for (int r = 0; r < 4; ++r) {
            const float* ap = A + (size_t)(row0 + r * 16 + l15) * K + k0 + lhi * 8;
            float4 a0 = ((const float4*)ap)[0];
            float4 a1 = ((const float4*)ap)[1];
            short8v t;
            t[0] = (short)f2bf(a0.x); t[1] = (short)f2bf(a0.y);
            t[2] = (short)f2bf(a0.z); t[3] = (short)f2bf(a0.w);
            t[4] = (short)f2bf(a1.x); t[5] = (short)f2bf(a1.y);
            t[6] = (short)f2bf(a1.z); t[7] = (short)f2bf(a1.w);
            afr[r] = t;
        }
#pragma unroll
        for (int q = 0; q < 4; ++q)
#pragma unroll
            for (int r = 0; r < 4; ++r)
                acc[q][r] = __builtin_amdgcn_mfma_f32_16x16x32_bf16(wfr[q], afr[r], acc[q][r], 0, 0, 0);
    }

#pragma unroll
    for (int r = 0; r < 4; ++r) {
        int m = row0 + r * 16 + l15;
        if (m < N) {
            f32x4 o4[4];
#pragma unroll
            for (int q = 0; q < 4; ++q) {
                int n0 = ncol0 + q * 16 + lhi * 4;
                f32x4 v = acc[q][r];
                f32x4 o;
#pragma unroll
                for (int i = 0; i < 4; ++i)
                    o[i] = fmaxf(v[i] * scale[q][i] + shift[q][i], 0.0f);
                o4[q] = o;
                if (AW) *(f32x4*)(aggr_out + (size_t)m * 256 + n0) = o;
            }
            us8 lo, hi;
#pragma unroll
            for (int q = 0; q < 4; ++q)
#pragma unroll
                for (int i = 0; i < 4; ++i) {
                    int p = i * 4 + q;
                    unsigned short v = f2bf(o4[q][i]);
                    if (p < 8) lo[p] = v; else hi[p - 8] = v;
                }
            *(us8*)(out + (size_t)m * 256 + ncol0 + lhi * 16) = lo;
            *(us8*)(out + (size_t)m * 256 + ncol0 + lhi * 16 + 8) = hi;
        }
    }
}

// Fused global-mean-pool + MLP head (h in PERMUTED bf16; w4t pre-permuted).
__global__ __launch_bounds__(256) void k_pool_head(
    const unsigned short* __restrict__ h, const int* __restrict__ gptr,
    const float* __restrict__ w4t, const float* __restrict__ b4,
    const float* __restrict__ w5, const float* __restrict__ b5,
    float* __restrict__ out)
{
    __shared__ float pl[256];
    __shared__ float zs[128];
    const int g = blockIdx.x;
    const int tid = threadIdx.x;
    int beg = gptr[g], end = gptr[g + 1];
    float acc = 0.0f;
    for (int r = beg; r < end; ++r) acc += bf2f(h[(size_t)r * 256 + tid]);
    float cnt = (float)(end - beg);
    pl[tid] = acc / fmaxf(cnt, 1.0f);
    __syncthreads();
    if (tid < 128) {
        float a = b4[tid];
        for (int k = 0; k < 256; ++k) a += pl[k] * w4t[k * 128 + tid];
        zs[tid] = fmaxf(a, 0.0f);
    }
    __syncthreads();
    if (tid < 64) {
        float v = zs[tid] * w5[tid] + zs[tid + 64] * w5[tid + 64];
#pragma unroll
        for (int off = 32; off > 0; off >>= 1) v += __shfl_down(v, off);
        if (tid == 0) out[g] = 1.0f / (1.0f + expf(-(v + b5[0])));
    }
}

extern "C" void kernel_launch(void* const* d_in, const int* in_sizes, int n_in,
                              void* d_out, int out_size, void* d_ws, size_t ws_size,
                              hipStream_t stream)
{
    const float* x    = (const float*)d_in[0];
    const int*   ei   = (const int*)d_in[1];
    const float* ea   = (const float*)d_in[2];
    const int*   batch= (const int*)d_in[3];
    const float* we1  = (const float*)d_in[4];
    const float* be1  = (const float*)d_in[5];
    const float* wn1  = (const float*)d_in[6];
    const float* bnb1 = (const float*)d_in[7];
    const float* we2  = (const float*)d_in[8];
    const float* be2  = (const float*)d_in[9];
    const float* wn2  = (const float*)d_in[10];
    const float* bnb2 = (const float*)d_in[11];
    const float* we3  = (const float*)d_in[12];
    const float* be3  = (const float*)d_in[13];
    const float* wn3  = (const float*)d_in[14];
    const float* bnb3 = (const float*)d_in[15];
    const float* g1 = (const float*)d_in[16];
    const float* b1 = (const float*)d_in[17];
    const float* rm1= (const float*)d_in[18];
    const float* rv1= (const float*)d_in[19];
    const float* g2 = (const float*)d_in[20];
    const float* b2 = (const float*)d_in[21];
    const float* rm2= (const float*)d_in[22];
    const float* rv2= (const float*)d_in[23];
    const float* g3 = (const float*)d_in[24];
    const float* b3 = (const float*)d_in[25];
    const float* rm3= (const float*)d_in[26];
    const float* rv3= (const float*)d_in[27];
    const float* w4 = (const float*)d_in[28];
    const float* b4 = (const float*)d_in[29];
    const float* w5 = (const float*)d_in[30];
    const float* b5 = (const float*)d_in[31];

    const int N = in_sizes[0] / 64;
    const int E = in_sizes[1] / 2;
    const int G = out_size;
    const int Epad = (E + 63) & ~63;
    const int npart = (N + 255) / 256;

    // ---- workspace layout ----
    float* ws    = (float*)d_ws;
    float* aggrA = ws;                                  // N*256 f32
    float* aggrB = aggrA + (size_t)N * 256;             // N*256 f32
    float* w4t   = aggrB + (size_t)N * 256;             // 256*128
    unsigned short* ea_s  = (unsigned short*)(w4t + 256 * 128);   // Epad*32 bf16
    unsigned short* x_bf  = ea_s + (size_t)Epad * 32;   // N*64 bf16 (permuted)
    unsigned short* h_bf  = x_bf + (size_t)N * 64;      // N*256 bf16 (permuted)
    unsigned short* webf1 = h_bf + (size_t)N * 256;     // 64*32 bf16
    unsigned short* webf2 = webf1 + 64 * 32;            // 256*32
    unsigned short* webf3 = webf2 + 256 * 32;           // 256*32
    unsigned short* wnbf1 = webf3 + 256 * 32;           // 256*64 bf16
    unsigned short* wnbf2 = wnbf1 + 256 * 64;           // 256*256
    unsigned short* wnbf3 = wnbf2 + 256 * 256;          // 256*256
    int* iws    = (int*)(wnbf3 + 256 * 256);
    int* ideg   = iws;                                  // N   (gcnt adjacent!)
    int* gcnt   = ideg + N;                             // G
    int* rowptr = gcnt + G;                             // N+1
    int* gptr   = rowptr + N + 1;                       // G+1
    int* cursor = gptr + G + 1;                         // N
    int* eid_s  = cursor + N;                           // E
    int* esrc_s = eid_s + E;                            // Epad
    int* dst_s  = esrc_s + Epad;                        // Epad
    int* part   = dst_s + Epad;                         // npart
    int* part_s = part + npart;                         // npart+1

    const int nblk64  = (N + 63) / 64;
    const int eblk256 = (E + 63) / 64;
    const int eblk64  = (E + 255) / 256;

    // ---- fused preprocessing ----
    k_zero_i<<<64, 256, 0, stream>>>(ideg, N + G);
    k_hist2<<<640, 256, 0, stream>>>(ei + E, E, batch, N, ideg, gcnt);
    k_scan_part<<<npart, 256, 0, stream>>>(ideg, part, N);
    k_scan_mid<<<1, 1024, 0, stream>>>(part, part_s, npart, gcnt, gptr, G, rowptr, N);
    k_scan_out<<<npart, 256, 0, stream>>>(ideg, part_s, rowptr, cursor, N);
    k_scatter<<<512, 256, 0, stream>>>(ei, E, Epad, cursor, eid_s, esrc_s, dst_s, ea_s);
    k_permute_ea<<<2048, 256, 0, stream>>>(ea, eid_s, ea_s, E);
    k_wprep<<<194, 256, 0, stream>>>(we1, we2, we3, wn1, wn2, wn3, w4,
                                     webf1, webf2, webf3, wnbf1, wnbf2, wnbf3, w4t);
    k_xprep<<<1250, 256, 0, stream>>>(x, x_bf, aggrA, N * 16);

    // ---- Layer 1 (D=64) ----
    k_edge_mfma<64><<<eblk64, 256, 0, stream>>>(
        x_bf, ea_s, esrc_s, dst_s, webf1, be1, aggrA, E);
    k_node_mfma<64, true><<<nblk64, 256, 0, stream>>>(aggrA, wnbf1, bnb1, g1, b1, rm1, rv1,
                                                      h_bf, aggrB, N);

    // ---- Layer 2 (D=256) ----
    k_edge_mfma<256><<<eblk256, 256, 0, stream>>>(
        h_bf, ea_s, esrc_s, dst_s, webf2, be2, aggrB, E);
    k_node_mfma<256, true><<<nblk64, 256, 0, stream>>>(aggrB, wnbf2, bnb2, g2, b2, rm2, rv2,
                                                       h_bf, aggrA, N);

    // ---- Layer 3 (D=256) ----
    k_edge_mfma<256><<<eblk256, 256, 0, stream>>>(
        h_bf, ea_s, esrc_s, dst_s, webf3, be3, aggrA, E);
    k_node_mfma<256, false><<<nblk64, 256, 0, stream>>>(aggrA, wnbf3, bnb3, g3, b3, rm3, rv3,
                                                        h_bf, (float*)nullptr, N);

    // ---- Fused pool + head ----
    k_pool_head<<<G, 256, 0, stream>>>(h_bf, gptr, w4t, b4, w5, b5, (float*)d_out);
}

// Round 11
// 708.169 us; speedup vs baseline: 1.5963x; 1.5963x over previous
//
#include <hip/hip_runtime.h>
#include <hip/hip_bf16.h>
#include <math.h>

// ---------------------------------------------------------------------------
// GINE model: 3x (GINEConv + BN + ReLU) -> global mean pool -> MLP -> sigmoid
// Round 11: round-9 edge structure + serial in-lane run-sum flush (consecutive
// edge rows per lane) with predicated atomic emission. No LDS, no ballot.
// LDS atomics proven catastrophic (round 10); never again.
// ---------------------------------------------------------------------------

typedef __attribute__((ext_vector_type(8))) short short8v;
typedef __attribute__((ext_vector_type(4))) float f32x4;
typedef __attribute__((ext_vector_type(4))) unsigned short us4;
typedef __attribute__((ext_vector_type(8))) unsigned short us8;

static __device__ __forceinline__ float bf2f(unsigned short u) {
    union { unsigned int u32; float f; } c; c.u32 = ((unsigned int)u) << 16; return c.f;
}
static __device__ __forceinline__ unsigned short f2bf(float f) {
    union { float f; unsigned int u; } c; c.f = f;
    unsigned int lsb = (c.u >> 16) & 1u;
    c.u += 0x7fffu + lsb;
    return (unsigned short)(c.u >> 16);
}

__global__ void k_zero_i(int* __restrict__ p, int n) {
    int i = blockIdx.x * blockDim.x + threadIdx.x;
    int st = gridDim.x * blockDim.x;
    for (; i < n; i += st) p[i] = 0;
}

// dst histogram (blocks 0..511) + batch histogram (blocks 512..639)
__global__ void k_hist2(const int* __restrict__ dst, int E,
                        const int* __restrict__ batch, int N,
                        int* __restrict__ ideg, int* __restrict__ gcnt) {
    int b = blockIdx.x;
    if (b < 512) {
        int i = b * 256 + threadIdx.x, st = 512 * 256;
        for (; i < E; i += st) atomicAdd(&ideg[dst[i]], 1);
    } else {
        int i = (b - 512) * 256 + threadIdx.x, st = 128 * 256;
        for (; i < N; i += st) atomicAdd(&gcnt[batch[i]], 1);
    }
}

// ---- multi-block scan: part -> mid -> out ----
__global__ __launch_bounds__(256) void k_scan_part(const int* __restrict__ in,
                                                   int* __restrict__ part, int n) {
    __shared__ int wtot[4];
    const int tid = threadIdx.x, lane = tid & 63, wv = tid >> 6;
    int i = blockIdx.x * 256 + tid;
    int s = (i < n) ? in[i] : 0;
#pragma unroll
    for (int off = 1; off < 64; off <<= 1) s += __shfl_xor(s, off);
    if (lane == 0) wtot[wv] = s;
    __syncthreads();
    if (tid == 0) part[blockIdx.x] = wtot[0] + wtot[1] + wtot[2] + wtot[3];
}

static __device__ void scan_block(const int* __restrict__ in, int* __restrict__ out,
                                  int n, int* wsum) {
    const int tid = threadIdx.x;
    const int lane = tid & 63, wv = tid >> 6;
    const int C = (n + 1023) >> 10;
    const int base = tid * C;
    int s = 0;
    for (int k = 0; k < C; ++k) {
        int i = base + k;
        if (i < n) s += in[i];
    }
    int incl = s;
#pragma unroll
    for (int off = 1; off < 64; off <<= 1) {
        int t = __shfl_up(incl, off);
        if (lane >= off) incl += t;
    }
    if (lane == 63) wsum[wv] = incl;
    __syncthreads();
    int woff = 0;
    for (int i2 = 0; i2 < wv; ++i2) woff += wsum[i2];
    int run = woff + incl - s;
    for (int k = 0; k < C; ++k) {
        int i = base + k;
        if (i < n) {
            out[i] = run;
            run += in[i];
        }
    }
    if (tid == 1023) out[n] = run;
    __syncthreads();
}

__global__ __launch_bounds__(1024) void k_scan_mid(
    const int* __restrict__ part, int* __restrict__ part_s, int npart,
    const int* __restrict__ gcnt, int* __restrict__ gptr, int G,
    int* __restrict__ rowptr, int N) {
    __shared__ int wsum[16];
    scan_block(part, part_s, npart, wsum);
    if (threadIdx.x == 0) rowptr[N] = part_s[npart];
    scan_block(gcnt, gptr, G, wsum);
}

__global__ __launch_bounds__(256) void k_scan_out(const int* __restrict__ in,
                                                  const int* __restrict__ part_s,
                                                  int* __restrict__ rowptr,
                                                  int* __restrict__ cursor, int n) {
    __shared__ int wtot[4];
    const int tid = threadIdx.x, lane = tid & 63, wv = tid >> 6;
    int i = blockIdx.x * 256 + tid;
    int v = (i < n) ? in[i] : 0;
    int s = v;
#pragma unroll
    for (int off = 1; off < 64; off <<= 1) {
        int t = __shfl_up(s, off);
        if (lane >= off) s += t;
    }
    if (lane == 63) wtot[wv] = s;
    __syncthreads();
    int woff = 0;
    for (int k = 0; k < wv; ++k) woff += wtot[k];
    int excl = part_s[blockIdx.x] + woff + s - v;
    if (i < n) { rowptr[i] = excl; cursor[i] = excl; }
}

// bucket edges by dst + pad tail [E, Epad)
__global__ void k_scatter(const int* __restrict__ ei, int E, int Epad,
                          int* __restrict__ cursor, int* __restrict__ eid_s,
                          int* __restrict__ esrc_s, int* __restrict__ dst_s,
                          unsigned short* __restrict__ ea_s) {
    int i = blockIdx.x * blockDim.x + threadIdx.x;
    int st = gridDim.x * blockDim.x;
    for (int k = i; k < E; k += st) {
        int d = ei[E + k];
        int pos = atomicAdd(&cursor[d], 1);
        eid_s[pos] = k;
        esrc_s[pos] = ei[k];
        dst_s[pos] = d;
    }
    if (i < Epad - E) {
        esrc_s[E + i] = 0;
        dst_s[E + i] = -1;
        us4 z = {0, 0, 0, 0};
        us4* p = (us4*)(ea_s + (size_t)(E + i) * 32);
#pragma unroll
        for (int q = 0; q < 8; ++q) p[q] = z;
    }
}

// ea_s[pos] = bf16(ea[eid_s[pos]]), CSR order
__global__ void k_permute_ea(const float* __restrict__ ea, const int* __restrict__ eid_s,
                             unsigned short* __restrict__ ea_s, int E) {
    int i = blockIdx.x * blockDim.x + threadIdx.x;
    int st = gridDim.x * blockDim.x;
    const int ng = E * 4;
    for (; i < ng; i += st) {
        int pos = i >> 2, q = i & 3;
        int e = eid_s[pos];
        const float4* sp = (const float4*)(ea + (size_t)e * 32 + q * 8);
        float4 a = sp[0], b = sp[1];
        us4 o0, o1;
        o0.x = f2bf(a.x); o0.y = f2bf(a.y); o0.z = f2bf(a.z); o0.w = f2bf(a.w);
        o1.x = f2bf(b.x); o1.y = f2bf(b.y); o1.z = f2bf(b.z); o1.w = f2bf(b.w);
        us4* dp = (us4*)(ea_s + (size_t)pos * 32 + q * 8);
        dp[0] = o0; dp[1] = o1;
    }
}

// weight prep: bf16 casts of we1/2/3, wn1/2/3 + w4 transpose with permuted rows
__global__ void k_wprep(const float* __restrict__ we1, const float* __restrict__ we2,
                        const float* __restrict__ we3, const float* __restrict__ wn1,
                        const float* __restrict__ wn2, const float* __restrict__ wn3,
                        const float* __restrict__ w4,
                        unsigned short* __restrict__ webf1, unsigned short* __restrict__ webf2,
                        unsigned short* __restrict__ webf3, unsigned short* __restrict__ wnbf1,
                        unsigned short* __restrict__ wnbf2, unsigned short* __restrict__ wnbf3,
                        float* __restrict__ w4t) {
    int idx = blockIdx.x * blockDim.x + threadIdx.x;
    const float* s; unsigned short* d; int rel;
    if (idx < 512)        { s = we1; d = webf1; rel = idx; }
    else if (idx < 2560)  { s = we2; d = webf2; rel = idx - 512; }
    else if (idx < 4608)  { s = we3; d = webf3; rel = idx - 2560; }
    else if (idx < 8704)  { s = wn1; d = wnbf1; rel = idx - 4608; }
    else if (idx < 25088) { s = wn2; d = wnbf2; rel = idx - 8704; }
    else if (idx < 41472) { s = wn3; d = wnbf3; rel = idx - 25088; }
    else if (idx < 49664) {
        int rel2 = idx - 41472;
        int k = rel2 >> 5;                 // position 0..255 in permuted pooled vec
        int j0 = (rel2 & 31) * 4;
        int ck = (k & 0xC0) | (((k & 3) * 16) + ((k & 63) >> 2));
        float4 o;
        o.x = w4[(j0 + 0) * 256 + ck]; o.y = w4[(j0 + 1) * 256 + ck];
        o.z = w4[(j0 + 2) * 256 + ck]; o.w = w4[(j0 + 3) * 256 + ck];
        *(float4*)(w4t + k * 128 + j0) = o;
        return;
    } else return;
    float4 t = ((const float4*)s)[rel];
    us4 o; o.x = f2bf(t.x); o.y = f2bf(t.y); o.z = f2bf(t.z); o.w = f2bf(t.w);
    ((us4*)d)[rel] = o;
}

// x -> permuted bf16 x_bf + natural f32 self-term init
__global__ void k_xprep(const float* __restrict__ x, unsigned short* __restrict__ x_bf,
                        float* __restrict__ aggrA, int n16) {
    int i = blockIdx.x * blockDim.x + threadIdx.x;
    int st = gridDim.x * blockDim.x;
    for (; i < n16; i += st) {
        int n = i >> 4, j = i & 15;
        float4 t = *(const float4*)(x + (size_t)n * 64 + j * 4);
        ((float4*)aggrA)[i] = t;
        us4 o;
        o.x = f2bf(x[(size_t)n * 64 + j]);
        o.y = f2bf(x[(size_t)n * 64 + 16 + j]);
        o.z = f2bf(x[(size_t)n * 64 + 32 + j]);
        o.w = f2bf(x[(size_t)n * 64 + 48 + j]);
        *(us4*)(x_bf + (size_t)n * 64 + j * 4) = o;
    }
}

// ---------------------------------------------------------------------------
// Edge kernel. 1 tile (64 edges) per wave-group; D=256: 4 waves/block share
// the tile (64 cols each); D=64: each wave owns a tile. Permuted-h 8B gathers.
// Flush: per lane, its 4 accumulator rows per q-group are CONSECUTIVE edges
// -> serial run-sum over i with dst-change breaks, predicated atomicAdd per
// run. Runs spanning lanes/q/tiles merge via the atomics. No LDS, no ballot.
// aggr must be pre-initialized with the self term (f32, natural layout).
// ---------------------------------------------------------------------------
template<int D>
__global__ __launch_bounds__(256) void k_edge_mfma(
    const unsigned short* __restrict__ hbf,   // [N][D] bf16, PERMUTED layout
    const unsigned short* __restrict__ ea_s,  // [Epad][32] bf16, CSR order
    const int* __restrict__ esrc_s,           // [Epad]
    const int* __restrict__ dst_s,            // [Epad]
    const unsigned short* __restrict__ webf,  // [D][32] bf16, natural rows
    const float* __restrict__ be,             // [D]
    float* __restrict__ aggr,                 // [N][D] f32, natural layout
    int E)
{
    const int tid = threadIdx.x;
    const int lane = tid & 63;
    const int w = tid >> 6;
    const int l15 = lane & 15;
    const int lhi = lane >> 4;

    const int wavetile = (D == 256) ? (int)blockIdx.x : ((int)blockIdx.x * 4 + w);
    const int colbase  = (D == 256) ? (w * 64) : 0;
    const int e0 = wavetile * 64;
    if (e0 >= E) return;

    // src and dst rows for this lane's 4 consecutive edges per q-group
    int4 src4[4], dst4[4];
#pragma unroll
    for (int q = 0; q < 4; ++q) {
        src4[q] = *(const int4*)(esrc_s + e0 + q * 16 + lhi * 4);
        dst4[q] = *(const int4*)(dst_s + e0 + q * 16 + lhi * 4);
    }

    short8v afr[4];
#pragma unroll
    for (int q = 0; q < 4; ++q)
        afr[q] = *(const short8v*)(ea_s + (size_t)(e0 + q * 16 + l15) * 32 + lhi * 8);

    short8v bfr[4]; float bias[4];
#pragma unroll
    for (int t = 0; t < 4; ++t) {
        int c = colbase + t * 16 + l15;
        bfr[t] = *(const short8v*)(webf + (size_t)c * 32 + lhi * 8);
        bias[t] = be[c];
    }

    // permuted h-gather: one us4 per fragment row -> channels {t*16+l15}
    us4 hv[4][4];
#pragma unroll
    for (int q = 0; q < 4; ++q) {
        const int sr[4] = {src4[q].x, src4[q].y, src4[q].z, src4[q].w};
#pragma unroll
        for (int i = 0; i < 4; ++i)
            hv[q][i] = *(const us4*)(hbf + (size_t)sr[i] * D + colbase + l15 * 4);
    }

    f32x4 acc[4][4];
#pragma unroll
    for (int q = 0; q < 4; ++q)
#pragma unroll
        for (int t = 0; t < 4; ++t) {
            f32x4 ci; ci[0] = bias[t]; ci[1] = bias[t]; ci[2] = bias[t]; ci[3] = bias[t];
            acc[q][t] = __builtin_amdgcn_mfma_f32_16x16x32_bf16(afr[q], bfr[t], ci, 0, 0, 0);
        }

    // m = relu(el + h_src)
#pragma unroll
    for (int q = 0; q < 4; ++q)
#pragma unroll
        for (int i = 0; i < 4; ++i) {
            us4 h4 = hv[q][i];
#pragma unroll
            for (int t = 0; t < 4; ++t)
                acc[q][t][i] = fmaxf(acc[q][t][i] + bf2f(h4[t]), 0.0f);
        }

    // serial in-lane run-sum flush (rows lhi*4+i are consecutive edges)
#pragma unroll
    for (int q = 0; q < 4; ++q) {
        const int dd[4] = {dst4[q].x, dst4[q].y, dst4[q].z, dst4[q].w};
        float a[4];
#pragma unroll
        for (int t = 0; t < 4; ++t) a[t] = acc[q][t][0];
#pragma unroll
        for (int i = 1; i < 4; ++i) {
            bool brk = (dd[i] != dd[i - 1]);
            if (brk && dd[i - 1] >= 0) {
                float* base = aggr + (size_t)dd[i - 1] * D + colbase + l15;
#pragma unroll
                for (int t = 0; t < 4; ++t) atomicAdd(base + t * 16, a[t]);
            }
#pragma unroll
            for (int t = 0; t < 4; ++t)
                a[t] = (brk ? 0.0f : a[t]) + acc[q][t][i];
        }
        if (dd[3] >= 0) {
            float* base = aggr + (size_t)dd[3] * D + colbase + l15;
#pragma unroll
            for (int t = 0; t < 4; ++t) atomicAdd(base + t * 16, a[t]);
        }
    }
}

// ---------------------------------------------------------------------------
// MFMA node GEMM + BN + ReLU. Natural aggr in/out; h_bf stored PERMUTED via
// two 16B stores per row-fragment.
// ---------------------------------------------------------------------------
template<int K, bool AW>
__global__ __launch_bounds__(256) void k_node_mfma(
    const float* __restrict__ A, const unsigned short* __restrict__ wnbf,
    const float* __restrict__ bnb, const float* __restrict__ g,
    const float* __restrict__ b, const float* __restrict__ rm,
    const float* __restrict__ rv, unsigned short* __restrict__ out,
    float* __restrict__ aggr_out, int N)
{
    const int tid = threadIdx.x;
    const int lane = tid & 63;
    const int w = tid >> 6;
    const int l15 = lane & 15;
    const int lhi = lane >> 4;
    const int row0 = blockIdx.x * 64;
    const int ncol0 = w * 64;

    f32x4 scale[4], shift[4];
    f32x4 acc[4][4];
#pragma unroll
    for (int q = 0; q < 4; ++q) {
        int n0 = ncol0 + q * 16 + lhi * 4;
        float4 gg = *(const float4*)(g + n0);
        float4 rvv = *(const float4*)(rv + n0);
        float4 bb = *(const float4*)(b + n0);
        float4 rmm = *(const float4*)(rm + n0);
        float4 bn = *(const float4*)(bnb + n0);
        f32x4 sc, sh, ci;
        sc[0] = gg.x * rsqrtf(rvv.x + 1e-5f);
        sc[1] = gg.y * rsqrtf(rvv.y + 1e-5f);
        sc[2] = gg.z * rsqrtf(rvv.z + 1e-5f);
        sc[3] = gg.w * rsqrtf(rvv.w + 1e-5f);
        sh[0] = bb.x - rmm.x * sc[0];
        sh[1] = bb.y - rmm.y * sc[1];
        sh[2] = bb.z - rmm.z * sc[2];
        sh[3] = bb.w - rmm.w * sc[3];
        ci[0] = bn.x; ci[1] = bn.y; ci[2] = bn.z; ci[3] = bn.w;
        scale[q] = sc; shift[q] = sh;
#pragma unroll
        for (int r = 0; r < 4; ++r) acc[q][r] = ci;
    }

    for (int k0 = 0; k0 < K; k0 += 32) {
        short8v wfr[4];
#pragma unroll
        for (int q = 0; q < 4; ++q)
            wfr[q] = *(const short8v*)(wnbf + (size_t)(ncol0 + q * 16 + l15) * K + k0 + lhi * 8);
        short8v afr[4];
#pragma unroll
        for (int r = 0; r < 4; ++r) {
            const float* ap = A + (size_t)(row0 + r * 16 + l15) * K + k0 + lhi * 8;
            float4 a0 = ((const float4*)ap)[0];
            float4 a1 = ((const float4*)ap)[1];
            short8v t;
            t[0] = (short)f2bf(a0.x); t[1] = (short)f2bf(a0.y);
            t[2] = (short)f2bf(a0.z); t[3] = (short)f2bf(a0.w);
            t[4] = (short)f2bf(a1.x); t[5] = (short)f2bf(a1.y);
            t[6] = (short)f2bf(a1.z); t[7] = (short)f2bf(a1.w);
            afr[r] = t;
        }
#pragma unroll
        for (int q = 0; q < 4; ++q)
#pragma unroll
            for (int r = 0; r < 4; ++r)
                acc[q][r] = __builtin_amdgcn_mfma_f32_16x16x32_bf16(wfr[q], afr[r], acc[q][r], 0, 0, 0);
    }

#pragma unroll
    for (int r = 0; r < 4; ++r) {
        int m = row0 + r * 16 + l15;
        if (m < N) {
            f32x4 o4[4];
#pragma unroll
            for (int q = 0; q < 4; ++q) {
                int n0 = ncol0 + q * 16 + lhi * 4;
                f32x4 v = acc[q][r];
                f32x4 o;
#pragma unroll
                for (int i = 0; i < 4; ++i)
                    o[i] = fmaxf(v[i] * scale[q][i] + shift[q][i], 0.0f);
                o4[q] = o;
                if (AW) *(f32x4*)(aggr_out + (size_t)m * 256 + n0) = o;
            }
            us8 lo, hi;
#pragma unroll
            for (int q = 0; q < 4; ++q)
#pragma unroll
                for (int i = 0; i < 4; ++i) {
                    int p = i * 4 + q;
                    unsigned short v = f2bf(o4[q][i]);
                    if (p < 8) lo[p] = v; else hi[p - 8] = v;
                }
            *(us8*)(out + (size_t)m * 256 + ncol0 + lhi * 16) = lo;
            *(us8*)(out + (size_t)m * 256 + ncol0 + lhi * 16 + 8) = hi;
        }
    }
}

// Fused global-mean-pool + MLP head (h in PERMUTED bf16; w4t pre-permuted).
__global__ __launch_bounds__(256) void k_pool_head(
    const unsigned short* __restrict__ h, const int* __restrict__ gptr,
    const float* __restrict__ w4t, const float* __restrict__ b4,
    const float* __restrict__ w5, const float* __restrict__ b5,
    float* __restrict__ out)
{
    __shared__ float pl[256];
    __shared__ float zs[128];
    const int g = blockIdx.x;
    const int tid = threadIdx.x;
    int beg = gptr[g], end = gptr[g + 1];
    float acc = 0.0f;
    for (int r = beg; r < end; ++r) acc += bf2f(h[(size_t)r * 256 + tid]);
    float cnt = (float)(end - beg);
    pl[tid] = acc / fmaxf(cnt, 1.0f);
    __syncthreads();
    if (tid < 128) {
        float a = b4[tid];
        for (int k = 0; k < 256; ++k) a += pl[k] * w4t[k * 128 + tid];
        zs[tid] = fmaxf(a, 0.0f);
    }
    __syncthreads();
    if (tid < 64) {
        float v = zs[tid] * w5[tid] + zs[tid + 64] * w5[tid + 64];
#pragma unroll
        for (int off = 32; off > 0; off >>= 1) v += __shfl_down(v, off);
        if (tid == 0) out[g] = 1.0f / (1.0f + expf(-(v + b5[0])));
    }
}

extern "C" void kernel_launch(void* const* d_in, const int* in_sizes, int n_in,
                              void* d_out, int out_size, void* d_ws, size_t ws_size,
                              hipStream_t stream)
{
    const float* x    = (const float*)d_in[0];
    const int*   ei   = (const int*)d_in[1];
    const float* ea   = (const float*)d_in[2];
    const int*   batch= (const int*)d_in[3];
    const float* we1  = (const float*)d_in[4];
    const float* be1  = (const float*)d_in[5];
    const float* wn1  = (const float*)d_in[6];
    const float* bnb1 = (const float*)d_in[7];
    const float* we2  = (const float*)d_in[8];
    const float* be2  = (const float*)d_in[9];
    const float* wn2  = (const float*)d_in[10];
    const float* bnb2 = (const float*)d_in[11];
    const float* we3  = (const float*)d_in[12];
    const float* be3  = (const float*)d_in[13];
    const float* wn3  = (const float*)d_in[14];
    const float* bnb3 = (const float*)d_in[15];
    const float* g1 = (const float*)d_in[16];
    const float* b1 = (const float*)d_in[17];
    const float* rm1= (const float*)d_in[18];
    const float* rv1= (const float*)d_in[19];
    const float* g2 = (const float*)d_in[20];
    const float* b2 = (const float*)d_in[21];
    const float* rm2= (const float*)d_in[22];
    const float* rv2= (const float*)d_in[23];
    const float* g3 = (const float*)d_in[24];
    const float* b3 = (const float*)d_in[25];
    const float* rm3= (const float*)d_in[26];
    const float* rv3= (const float*)d_in[27];
    const float* w4 = (const float*)d_in[28];
    const float* b4 = (const float*)d_in[29];
    const float* w5 = (const float*)d_in[30];
    const float* b5 = (const float*)d_in[31];

    const int N = in_sizes[0] / 64;
    const int E = in_sizes[1] / 2;
    const int G = out_size;
    const int Epad = (E + 63) & ~63;
    const int npart = (N + 255) / 256;

    // ---- workspace layout ----
    float* ws    = (float*)d_ws;
    float* aggrA = ws;                                  // N*256 f32
    float* aggrB = aggrA + (size_t)N * 256;             // N*256 f32
    float* w4t   = aggrB + (size_t)N * 256;             // 256*128
    unsigned short* ea_s  = (unsigned short*)(w4t + 256 * 128);   // Epad*32 bf16
    unsigned short* x_bf  = ea_s + (size_t)Epad * 32;   // N*64 bf16 (permuted)
    unsigned short* h_bf  = x_bf + (size_t)N * 64;      // N*256 bf16 (permuted)
    unsigned short* webf1 = h_bf + (size_t)N * 256;     // 64*32 bf16
    unsigned short* webf2 = webf1 + 64 * 32;            // 256*32
    unsigned short* webf3 = webf2 + 256 * 32;           // 256*32
    unsigned short* wnbf1 = webf3 + 256 * 32;           // 256*64 bf16
    unsigned short* wnbf2 = wnbf1 + 256 * 64;           // 256*256
    unsigned short* wnbf3 = wnbf2 + 256 * 256;          // 256*256
    int* iws    = (int*)(wnbf3 + 256 * 256);
    int* ideg   = iws;                                  // N   (gcnt adjacent!)
    int* gcnt   = ideg + N;                             // G
    int* rowptr = gcnt + G;                             // N+1
    int* gptr   = rowptr + N + 1;                       // G+1
    int* cursor = gptr + G + 1;                         // N
    int* eid_s  = cursor + N;                           // E
    int* esrc_s = eid_s + E;                            // Epad
    int* dst_s  = esrc_s + Epad;                        // Epad
    int* part   = dst_s + Epad;                         // npart
    int* part_s = part + npart;                         // npart+1

    const int nblk64  = (N + 63) / 64;
    const int eblk256 = (E + 63) / 64;
    const int eblk64  = (E + 255) / 256;

    // ---- fused preprocessing ----
    k_zero_i<<<64, 256, 0, stream>>>(ideg, N + G);
    k_hist2<<<640, 256, 0, stream>>>(ei + E, E, batch, N, ideg, gcnt);
    k_scan_part<<<npart, 256, 0, stream>>>(ideg, part, N);
    k_scan_mid<<<1, 1024, 0, stream>>>(part, part_s, npart, gcnt, gptr, G, rowptr, N);
    k_scan_out<<<npart, 256, 0, stream>>>(ideg, part_s, rowptr, cursor, N);
    k_scatter<<<512, 256, 0, stream>>>(ei, E, Epad, cursor, eid_s, esrc_s, dst_s, ea_s);
    k_permute_ea<<<2048, 256, 0, stream>>>(ea, eid_s, ea_s, E);
    k_wprep<<<194, 256, 0, stream>>>(we1, we2, we3, wn1, wn2, wn3, w4,
                                     webf1, webf2, webf3, wnbf1, wnbf2, wnbf3, w4t);
    k_xprep<<<1250, 256, 0, stream>>>(x, x_bf, aggrA, N * 16);

    // ---- Layer 1 (D=64) ----
    k_edge_mfma<64><<<eblk64, 256, 0, stream>>>(
        x_bf, ea_s, esrc_s, dst_s, webf1, be1, aggrA, E);
    k_node_mfma<64, true><<<nblk64, 256, 0, stream>>>(aggrA, wnbf1, bnb1, g1, b1, rm1, rv1,
                                                      h_bf, aggrB, N);

    // ---- Layer 2 (D=256) ----
    k_edge_mfma<256><<<eblk256, 256, 0, stream>>>(
        h_bf, ea_s, esrc_s, dst_s, webf2, be2, aggrB, E);
    k_node_mfma<256, true><<<nblk64, 256, 0, stream>>>(aggrB, wnbf2, bnb2, g2, b2, rm2, rv2,
                                                       h_bf, aggrA, N);

    // ---- Layer 3 (D=256) ----
    k_edge_mfma<256><<<eblk256, 256, 0, stream>>>(
        h_bf, ea_s, esrc_s, dst_s, webf3, be3, aggrA, E);
    k_node_mfma<256, false><<<nblk64, 256, 0, stream>>>(aggrA, wnbf3, bnb3, g3, b3, rm3, rv3,
                                                        h_bf, (float*)nullptr, N);

    // ---- Fused pool + head ----
    k_pool_head<<<G, 256, 0, stream>>>(h_bf, gptr, w4t, b4, w5, b5, (float*)d_out);
}

// Round 12
// 332.818 us; speedup vs baseline: 3.3965x; 2.1278x over previous
//
#include <hip/hip_runtime.h>
#include <hip/hip_bf16.h>
#include <math.h>

// ---------------------------------------------------------------------------
// GINE model: 3x (GINEConv + BN + ReLU) -> global mean pool -> MLP -> sigmoid
// Round 12: round-9 edge structure, flush replaced by tile-wide prefix sum +
// telescoping emission (+P[r] -> dst[r], -P[r] -> dst[r+1] at segment ends).
// Messages ~1.8x round 9 (vs 3.3x round 11), flush VALU ~2.3x lower than r9.
// ---------------------------------------------------------------------------

typedef __attribute__((ext_vector_type(8))) short short8v;
typedef __attribute__((ext_vector_type(4))) float f32x4;
typedef __attribute__((ext_vector_type(4))) unsigned short us4;
typedef __attribute__((ext_vector_type(8))) unsigned short us8;

static __device__ __forceinline__ float bf2f(unsigned short u) {
    union { unsigned int u32; float f; } c; c.u32 = ((unsigned int)u) << 16; return c.f;
}
static __device__ __forceinline__ unsigned short f2bf(float f) {
    union { float f; unsigned int u; } c; c.f = f;
    unsigned int lsb = (c.u >> 16) & 1u;
    c.u += 0x7fffu + lsb;
    return (unsigned short)(c.u >> 16);
}

__global__ void k_zero_i(int* __restrict__ p, int n) {
    int i = blockIdx.x * blockDim.x + threadIdx.x;
    int st = gridDim.x * blockDim.x;
    for (; i < n; i += st) p[i] = 0;
}

// dst histogram (blocks 0..511) + batch histogram (blocks 512..639)
__global__ void k_hist2(const int* __restrict__ dst, int E,
                        const int* __restrict__ batch, int N,
                        int* __restrict__ ideg, int* __restrict__ gcnt) {
    int b = blockIdx.x;
    if (b < 512) {
        int i = b * 256 + threadIdx.x, st = 512 * 256;
        for (; i < E; i += st) atomicAdd(&ideg[dst[i]], 1);
    } else {
        int i = (b - 512) * 256 + threadIdx.x, st = 128 * 256;
        for (; i < N; i += st) atomicAdd(&gcnt[batch[i]], 1);
    }
}

// ---- multi-block scan: part -> mid -> out ----
__global__ __launch_bounds__(256) void k_scan_part(const int* __restrict__ in,
                                                   int* __restrict__ part, int n) {
    __shared__ int wtot[4];
    const int tid = threadIdx.x, lane = tid & 63, wv = tid >> 6;
    int i = blockIdx.x * 256 + tid;
    int s = (i < n) ? in[i] : 0;
#pragma unroll
    for (int off = 1; off < 64; off <<= 1) s += __shfl_xor(s, off);
    if (lane == 0) wtot[wv] = s;
    __syncthreads();
    if (tid == 0) part[blockIdx.x] = wtot[0] + wtot[1] + wtot[2] + wtot[3];
}

static __device__ void scan_block(const int* __restrict__ in, int* __restrict__ out,
                                  int n, int* wsum) {
    const int tid = threadIdx.x;
    const int lane = tid & 63, wv = tid >> 6;
    const int C = (n + 1023) >> 10;
    const int base = tid * C;
    int s = 0;
    for (int k = 0; k < C; ++k) {
        int i = base + k;
        if (i < n) s += in[i];
    }
    int incl = s;
#pragma unroll
    for (int off = 1; off < 64; off <<= 1) {
        int t = __shfl_up(incl, off);
        if (lane >= off) incl += t;
    }
    if (lane == 63) wsum[wv] = incl;
    __syncthreads();
    int woff = 0;
    for (int i2 = 0; i2 < wv; ++i2) woff += wsum[i2];
    int run = woff + incl - s;
    for (int k = 0; k < C; ++k) {
        int i = base + k;
        if (i < n) {
            out[i] = run;
            run += in[i];
        }
    }
    if (tid == 1023) out[n] = run;
    __syncthreads();
}

__global__ __launch_bounds__(1024) void k_scan_mid(
    const int* __restrict__ part, int* __restrict__ part_s, int npart,
    const int* __restrict__ gcnt, int* __restrict__ gptr, int G,
    int* __restrict__ rowptr, int N) {
    __shared__ int wsum[16];
    scan_block(part, part_s, npart, wsum);
    if (threadIdx.x == 0) rowptr[N] = part_s[npart];
    scan_block(gcnt, gptr, G, wsum);
}

__global__ __launch_bounds__(256) void k_scan_out(const int* __restrict__ in,
                                                  const int* __restrict__ part_s,
                                                  int* __restrict__ rowptr,
                                                  int* __restrict__ cursor, int n) {
    __shared__ int wtot[4];
    const int tid = threadIdx.x, lane = tid & 63, wv = tid >> 6;
    int i = blockIdx.x * 256 + tid;
    int v = (i < n) ? in[i] : 0;
    int s = v;
#pragma unroll
    for (int off = 1; off < 64; off <<= 1) {
        int t = __shfl_up(s, off);
        if (lane >= off) s += t;
    }
    if (lane == 63) wtot[wv] = s;
    __syncthreads();
    int woff = 0;
    for (int k = 0; k < wv; ++k) woff += wtot[k];
    int excl = part_s[blockIdx.x] + woff + s - v;
    if (i < n) { rowptr[i] = excl; cursor[i] = excl; }
}

// bucket edges by dst + pad tails: rows [E, Epad) fully; dst also [Epad, Epad+64)
__global__ void k_scatter(const int* __restrict__ ei, int E, int Epad,
                          int* __restrict__ cursor, int* __restrict__ eid_s,
                          int* __restrict__ esrc_s, int* __restrict__ dst_s,
                          unsigned short* __restrict__ ea_s) {
    int i = blockIdx.x * blockDim.x + threadIdx.x;
    int st = gridDim.x * blockDim.x;
    for (int k = i; k < E; k += st) {
        int d = ei[E + k];
        int pos = atomicAdd(&cursor[d], 1);
        eid_s[pos] = k;
        esrc_s[pos] = ei[k];
        dst_s[pos] = d;
    }
    if (i < Epad + 64 - E) {
        dst_s[E + i] = -1;
        if (i < Epad - E) {
            esrc_s[E + i] = 0;
            us4 z = {0, 0, 0, 0};
            us4* p = (us4*)(ea_s + (size_t)(E + i) * 32);
#pragma unroll
            for (int q = 0; q < 8; ++q) p[q] = z;
        }
    }
}

// ea_s[pos] = bf16(ea[eid_s[pos]]), CSR order
__global__ void k_permute_ea(const float* __restrict__ ea, const int* __restrict__ eid_s,
                             unsigned short* __restrict__ ea_s, int E) {
    int i = blockIdx.x * blockDim.x + threadIdx.x;
    int st = gridDim.x * blockDim.x;
    const int ng = E * 4;
    for (; i < ng; i += st) {
        int pos = i >> 2, q = i & 3;
        int e = eid_s[pos];
        const float4* sp = (const float4*)(ea + (size_t)e * 32 + q * 8);
        float4 a = sp[0], b = sp[1];
        us4 o0, o1;
        o0.x = f2bf(a.x); o0.y = f2bf(a.y); o0.z = f2bf(a.z); o0.w = f2bf(a.w);
        o1.x = f2bf(b.x); o1.y = f2bf(b.y); o1.z = f2bf(b.z); o1.w = f2bf(b.w);
        us4* dp = (us4*)(ea_s + (size_t)pos * 32 + q * 8);
        dp[0] = o0; dp[1] = o1;
    }
}

// weight prep: bf16 casts of we1/2/3, wn1/2/3 + w4 transpose with permuted rows
__global__ void k_wprep(const float* __restrict__ we1, const float* __restrict__ we2,
                        const float* __restrict__ we3, const float* __restrict__ wn1,
                        const float* __restrict__ wn2, const float* __restrict__ wn3,
                        const float* __restrict__ w4,
                        unsigned short* __restrict__ webf1, unsigned short* __restrict__ webf2,
                        unsigned short* __restrict__ webf3, unsigned short* __restrict__ wnbf1,
                        unsigned short* __restrict__ wnbf2, unsigned short* __restrict__ wnbf3,
                        float* __restrict__ w4t) {
    int idx = blockIdx.x * blockDim.x + threadIdx.x;
    const float* s; unsigned short* d; int rel;
    if (idx < 512)        { s = we1; d = webf1; rel = idx; }
    else if (idx < 2560)  { s = we2; d = webf2; rel = idx - 512; }
    else if (idx < 4608)  { s = we3; d = webf3; rel = idx - 2560; }
    else if (idx < 8704)  { s = wn1; d = wnbf1; rel = idx - 4608; }
    else if (idx < 25088) { s = wn2; d = wnbf2; rel = idx - 8704; }
    else if (idx < 41472) { s = wn3; d = wnbf3; rel = idx - 25088; }
    else if (idx < 49664) {
        int rel2 = idx - 41472;
        int k = rel2 >> 5;                 // position 0..255 in permuted pooled vec
        int j0 = (rel2 & 31) * 4;
        int ck = (k & 0xC0) | (((k & 3) * 16) + ((k & 63) >> 2));
        float4 o;
        o.x = w4[(j0 + 0) * 256 + ck]; o.y = w4[(j0 + 1) * 256 + ck];
        o.z = w4[(j0 + 2) * 256 + ck]; o.w = w4[(j0 + 3) * 256 + ck];
        *(float4*)(w4t + k * 128 + j0) = o;
        return;
    } else return;
    float4 t = ((const float4*)s)[rel];
    us4 o; o.x = f2bf(t.x); o.y = f2bf(t.y); o.z = f2bf(t.z); o.w = f2bf(t.w);
    ((us4*)d)[rel] = o;
}

// x -> permuted bf16 x_bf + natural f32 self-term init
__global__ void k_xprep(const float* __restrict__ x, unsigned short* __restrict__ x_bf,
                        float* __restrict__ aggrA, int n16) {
    int i = blockIdx.x * blockDim.x + threadIdx.x;
    int st = gridDim.x * blockDim.x;
    for (; i < n16; i += st) {
        int n = i >> 4, j = i & 15;
        float4 t = *(const float4*)(x + (size_t)n * 64 + j * 4);
        ((float4*)aggrA)[i] = t;
        us4 o;
        o.x = f2bf(x[(size_t)n * 64 + j]);
        o.y = f2bf(x[(size_t)n * 64 + 16 + j]);
        o.z = f2bf(x[(size_t)n * 64 + 32 + j]);
        o.w = f2bf(x[(size_t)n * 64 + 48 + j]);
        *(us4*)(x_bf + (size_t)n * 64 + j * 4) = o;
    }
}

// ---------------------------------------------------------------------------
// Edge kernel. 1 tile (64 edges); D=256: 4 waves/block share the tile (64
// cols each); D=64: each wave owns a tile. Permuted-h 8B gathers. Flush:
// tile-wide inclusive prefix P per channel (in-lane + shfl cross-lhi + carried
// cross-q), then telescoping emission at segment ends:
//   +P[r] -> dst[r], -P[r] -> dst[r+1]; tile-last row always ends (+P only).
// aggr must be pre-initialized with the self term (f32, natural layout).
// ---------------------------------------------------------------------------
template<int D>
__global__ __launch_bounds__(256) void k_edge_mfma(
    const unsigned short* __restrict__ hbf,   // [N][D] bf16, PERMUTED layout
    const unsigned short* __restrict__ ea_s,  // [Epad][32] bf16, CSR order
    const int* __restrict__ esrc_s,           // [Epad]
    const int* __restrict__ dst_s,            // [Epad+64], tail = -1
    const unsigned short* __restrict__ webf,  // [D][32] bf16, natural rows
    const float* __restrict__ be,             // [D]
    float* __restrict__ aggr,                 // [N][D] f32, natural layout
    int E)
{
    const int tid = threadIdx.x;
    const int lane = tid & 63;
    const int w = tid >> 6;
    const int l15 = lane & 15;
    const int lhi = lane >> 4;

    const int wavetile = (D == 256) ? (int)blockIdx.x : ((int)blockIdx.x * 4 + w);
    const int colbase  = (D == 256) ? (w * 64) : 0;
    const int e0 = wavetile * 64;
    if (e0 >= E) return;

    int4 src4[4], dst4[4];
#pragma unroll
    for (int q = 0; q < 4; ++q) {
        src4[q] = *(const int4*)(esrc_s + e0 + q * 16 + lhi * 4);
        dst4[q] = *(const int4*)(dst_s + e0 + q * 16 + lhi * 4);
    }

    short8v afr[4];
#pragma unroll
    for (int q = 0; q < 4; ++q)
        afr[q] = *(const short8v*)(ea_s + (size_t)(e0 + q * 16 + l15) * 32 + lhi * 8);

    short8v bfr[4]; float bias[4];
#pragma unroll
    for (int t = 0; t < 4; ++t) {
        int c = colbase + t * 16 + l15;
        bfr[t] = *(const short8v*)(webf + (size_t)c * 32 + lhi * 8);
        bias[t] = be[c];
    }

    // permuted h-gather: one us4 per fragment row -> channels {t*16+l15}
    us4 hv[4][4];
#pragma unroll
    for (int q = 0; q < 4; ++q) {
        const int sr[4] = {src4[q].x, src4[q].y, src4[q].z, src4[q].w};
#pragma unroll
        for (int i = 0; i < 4; ++i)
            hv[q][i] = *(const us4*)(hbf + (size_t)sr[i] * D + colbase + l15 * 4);
    }

    f32x4 acc[4][4];
#pragma unroll
    for (int q = 0; q < 4; ++q)
#pragma unroll
        for (int t = 0; t < 4; ++t) {
            f32x4 ci; ci[0] = bias[t]; ci[1] = bias[t]; ci[2] = bias[t]; ci[3] = bias[t];
            acc[q][t] = __builtin_amdgcn_mfma_f32_16x16x32_bf16(afr[q], bfr[t], ci, 0, 0, 0);
        }

    // m = relu(el + h_src)
#pragma unroll
    for (int q = 0; q < 4; ++q)
#pragma unroll
        for (int i = 0; i < 4; ++i) {
            us4 h4 = hv[q][i];
#pragma unroll
            for (int t = 0; t < 4; ++t)
                acc[q][t][i] = fmaxf(acc[q][t][i] + bf2f(h4[t]), 0.0f);
        }

    // ---- tile-wide inclusive prefix (in place on acc) ----
    float carry[4] = {0.0f, 0.0f, 0.0f, 0.0f};
#pragma unroll
    for (int q = 0; q < 4; ++q)
#pragma unroll
        for (int t = 0; t < 4; ++t) {
            acc[q][t][1] += acc[q][t][0];
            acc[q][t][2] += acc[q][t][1];
            acc[q][t][3] += acc[q][t][2];
            float g = acc[q][t][3];
            float g1 = __shfl_up(g, 16);
            if (lhi >= 1) g += g1;
            float g2 = __shfl_up(g, 32);
            if (lhi >= 2) g += g2;
            float tqv = __shfl(g, 48 + l15);        // subtile total (lhi=3 incl)
            float excl = g - acc[q][t][3] + carry[t];
            acc[q][t][0] += excl; acc[q][t][1] += excl;
            acc[q][t][2] += excl; acc[q][t][3] += excl;
            carry[t] += tqv;
        }

    // ---- telescoping emission at segment ends ----
#pragma unroll
    for (int q = 0; q < 4; ++q) {
        const int dd[4] = {dst4[q].x, dst4[q].y, dst4[q].z, dst4[q].w};
        int dnext = dst_s[e0 + q * 16 + lhi * 4 + 4];
        if (q == 3 && lhi == 3) dnext = -2;          // tile-last row: force end, no -P
        const int nx[4] = {dd[1], dd[2], dd[3], dnext};
#pragma unroll
        for (int i = 0; i < 4; ++i) {
            bool isend = (dd[i] != nx[i]);
            if (isend && dd[i] >= 0) {
                float* base = aggr + (size_t)dd[i] * D + colbase + l15;
#pragma unroll
                for (int t = 0; t < 4; ++t) atomicAdd(base + t * 16, acc[q][t][i]);
            }
            if (isend && nx[i] >= 0) {
                float* base = aggr + (size_t)nx[i] * D + colbase + l15;
#pragma unroll
                for (int t = 0; t < 4; ++t) atomicAdd(base + t * 16, -acc[q][t][i]);
            }
        }
    }
}

// ---------------------------------------------------------------------------
// MFMA node GEMM + BN + ReLU. Natural aggr in/out; h_bf stored PERMUTED via
// two 16B stores per row-fragment.
// ---------------------------------------------------------------------------
template<int K, bool AW>
__global__ __launch_bounds__(256) void k_node_mfma(
    const float* __restrict__ A, const unsigned short* __restrict__ wnbf,
    const float* __restrict__ bnb, const float* __restrict__ g,
    const float* __restrict__ b, const float* __restrict__ rm,
    const float* __restrict__ rv, unsigned short* __restrict__ out,
    float* __restrict__ aggr_out, int N)
{
    const int tid = threadIdx.x;
    const int lane = tid & 63;
    const int w = tid >> 6;
    const int l15 = lane & 15;
    const int lhi = lane >> 4;
    const int row0 = blockIdx.x * 64;
    const int ncol0 = w * 64;

    f32x4 scale[4], shift[4];
    f32x4 acc[4][4];
#pragma unroll
    for (int q = 0; q < 4; ++q) {
        int n0 = ncol0 + q * 16 + lhi * 4;
        float4 gg = *(const float4*)(g + n0);
        float4 rvv = *(const float4*)(rv + n0);
        float4 bb = *(const float4*)(b + n0);
        float4 rmm = *(const float4*)(rm + n0);
        float4 bn = *(const float4*)(bnb + n0);
        f32x4 sc, sh, ci;
        sc[0] = gg.x * rsqrtf(rvv.x + 1e-5f);
        sc[1] = gg.y * rsqrtf(rvv.y + 1e-5f);
        sc[2] = gg.z * rsqrtf(rvv.z + 1e-5f);
        sc[3] = gg.w * rsqrtf(rvv.w + 1e-5f);
        sh[0] = bb.x - rmm.x * sc[0];
        sh[1] = bb.y - rmm.y * sc[1];
        sh[2] = bb.z - rmm.z * sc[2];
        sh[3] = bb.w - rmm.w * sc[3];
        ci[0] = bn.x; ci[1] = bn.y; ci[2] = bn.z; ci[3] = bn.w;
        scale[q] = sc; shift[q] = sh;
#pragma unroll
        for (int r = 0; r < 4; ++r) acc[q][r] = ci;
    }

    for (int k0 = 0; k0 < K; k0 += 32) {
        short8v wfr[4];
#pragma unroll
        for (int q = 0; q < 4; ++q)
            wfr[q] = *(const short8v*)(wnbf + (size_t)(ncol0 + q * 16 + l15) * K + k0 + lhi * 8);
        short8v afr[4];
#pragma unroll
        for (int r = 0; r < 4; ++r) {
            const float* ap = A + (size_t)(row0 + r * 16 + l15) * K + k0 + lhi * 8;
            float4 a0 = ((const float4*)ap)[0];
            float4 a1 = ((const float4*)ap)[1];
            short8v t;
            t[0] = (short)f2bf(a0.x); t[1] = (short)f2bf(a0.y);
            t[2] = (short)f2bf(a0.z); t[3] = (short)f2bf(a0.w);
            t[4] = (short)f2bf(a1.x); t[5] = (short)f2bf(a1.y);
            t[6] = (short)f2bf(a1.z); t[7] = (short)f2bf(a1.w);
            afr[r] = t;
        }
#pragma unroll
        for (int q = 0; q < 4; ++q)
#pragma unroll
            for (int r = 0; r < 4; ++r)
                acc[q][r] = __builtin_amdgcn_mfma_f32_16x16x32_bf16(wfr[q], afr[r], acc[q][r], 0, 0, 0);
    }

#pragma unroll
    for (int r = 0; r < 4; ++r) {
        int m = row0 + r * 16 + l15;
        if (m < N) {
            f32x4 o4[4];
#pragma unroll
            for (int q = 0; q < 4; ++q) {
                int n0 = ncol0 + q * 16 + lhi * 4;
                f32x4 v = acc[q][r];
                f32x4 o;
#pragma unroll
                for (int i = 0; i < 4; ++i)
                    o[i] = fmaxf(v[i] * scale[q][i] + shift[q][i], 0.0f);
                o4[q] = o;
                if (AW) *(f32x4*)(aggr_out + (size_t)m * 256 + n0) = o;
            }
            us8 lo, hi;
#pragma unroll
            for (int q = 0; q < 4; ++q)
#pragma unroll
                for (int i = 0; i < 4; ++i) {
                    int p = i * 4 + q;
                    unsigned short v = f2bf(o4[q][i]);
                    if (p < 8) lo[p] = v; else hi[p - 8] = v;
                }
            *(us8*)(out + (size_t)m * 256 + ncol0 + lhi * 16) = lo;
            *(us8*)(out + (size_t)m * 256 + ncol0 + lhi * 16 + 8) = hi;
        }
    }
}

// Fused global-mean-pool + MLP head (h in PERMUTED bf16; w4t pre-permuted).
__global__ __launch_bounds__(256) void k_pool_head(
    const unsigned short* __restrict__ h, const int* __restrict__ gptr,
    const float* __restrict__ w4t, const float* __restrict__ b4,
    const float* __restrict__ w5, const float* __restrict__ b5,
    float* __restrict__ out)
{
    __shared__ float pl[256];
    __shared__ float zs[128];
    const int g = blockIdx.x;
    const int tid = threadIdx.x;
    int beg = gptr[g], end = gptr[g + 1];
    float acc = 0.0f;
    for (int r = beg; r < end; ++r) acc += bf2f(h[(size_t)r * 256 + tid]);
    float cnt = (float)(end - beg);
    pl[tid] = acc / fmaxf(cnt, 1.0f);
    __syncthreads();
    if (tid < 128) {
        float a = b4[tid];
        for (int k = 0; k < 256; ++k) a += pl[k] * w4t[k * 128 + tid];
        zs[tid] = fmaxf(a, 0.0f);
    }
    __syncthreads();
    if (tid < 64) {
        float v = zs[tid] * w5[tid] + zs[tid + 64] * w5[tid + 64];
#pragma unroll
        for (int off = 32; off > 0; off >>= 1) v += __shfl_down(v, off);
        if (tid == 0) out[g] = 1.0f / (1.0f + expf(-(v + b5[0])));
    }
}

extern "C" void kernel_launch(void* const* d_in, const int* in_sizes, int n_in,
                              void* d_out, int out_size, void* d_ws, size_t ws_size,
                              hipStream_t stream)
{
    const float* x    = (const float*)d_in[0];
    const int*   ei   = (const int*)d_in[1];
    const float* ea   = (const float*)d_in[2];
    const int*   batch= (const int*)d_in[3];
    const float* we1  = (const float*)d_in[4];
    const float* be1  = (const float*)d_in[5];
    const float* wn1  = (const float*)d_in[6];
    const float* bnb1 = (const float*)d_in[7];
    const float* we2  = (const float*)d_in[8];
    const float* be2  = (const float*)d_in[9];
    const float* wn2  = (const float*)d_in[10];
    const float* bnb2 = (const float*)d_in[11];
    const float* we3  = (const float*)d_in[12];
    const float* be3  = (const float*)d_in[13];
    const float* wn3  = (const float*)d_in[14];
    const float* bnb3 = (const float*)d_in[15];
    const float* g1 = (const float*)d_in[16];
    const float* b1 = (const float*)d_in[17];
    const float* rm1= (const float*)d_in[18];
    const float* rv1= (const float*)d_in[19];
    const float* g2 = (const float*)d_in[20];
    const float* b2 = (const float*)d_in[21];
    const float* rm2= (const float*)d_in[22];
    const float* rv2= (const float*)d_in[23];
    const float* g3 = (const float*)d_in[24];
    const float* b3 = (const float*)d_in[25];
    const float* rm3= (const float*)d_in[26];
    const float* rv3= (const float*)d_in[27];
    const float* w4 = (const float*)d_in[28];
    const float* b4 = (const float*)d_in[29];
    const float* w5 = (const float*)d_in[30];
    const float* b5 = (const float*)d_in[31];

    const int N = in_sizes[0] / 64;
    const int E = in_sizes[1] / 2;
    const int G = out_size;
    const int Epad = (E + 63) & ~63;
    const int npart = (N + 255) / 256;

    // ---- workspace layout (all arrays kept 16B-aligned) ----
    float* ws    = (float*)d_ws;
    float* aggrA = ws;                                  // N*256 f32
    float* aggrB = aggrA + (size_t)N * 256;             // N*256 f32
    float* w4t   = aggrB + (size_t)N * 256;             // 256*128
    unsigned short* ea_s  = (unsigned short*)(w4t + 256 * 128);   // Epad*32 bf16
    unsigned short* x_bf  = ea_s + (size_t)Epad * 32;   // N*64 bf16 (permuted)
    unsigned short* h_bf  = x_bf + (size_t)N * 64;      // N*256 bf16 (permuted)
    unsigned short* webf1 = h_bf + (size_t)N * 256;     // 64*32 bf16
    unsigned short* webf2 = webf1 + 64 * 32;            // 256*32
    unsigned short* webf3 = webf2 + 256 * 32;           // 256*32
    unsigned short* wnbf1 = webf3 + 256 * 32;           // 256*64 bf16
    unsigned short* wnbf2 = wnbf1 + 256 * 64;           // 256*256
    unsigned short* wnbf3 = wnbf2 + 256 * 256;          // 256*256
    int* iws    = (int*)(wnbf3 + 256 * 256);
    int* ideg   = iws;                                  // N   (gcnt adjacent!)
    int* gcnt   = ideg + N;                             // G
    int* rowptr = gcnt + G;                             // N+16 (padded for align)
    int* gptr   = rowptr + N + 16;                      // G+16
    int* cursor = gptr + G + 16;                        // N
    int* eid_s  = cursor + N;                           // E
    int* esrc_s = eid_s + E;                            // Epad
    int* dst_s  = esrc_s + Epad;                        // Epad+64 (tail -1)
    int* part   = dst_s + Epad + 64;                    // npart
    int* part_s = part + npart;                         // npart+1

    const int nblk64  = (N + 63) / 64;
    const int eblk256 = (E + 63) / 64;
    const int eblk64  = (E + 255) / 256;

    // ---- fused preprocessing ----
    k_zero_i<<<64, 256, 0, stream>>>(ideg, N + G);
    k_hist2<<<640, 256, 0, stream>>>(ei + E, E, batch, N, ideg, gcnt);
    k_scan_part<<<npart, 256, 0, stream>>>(ideg, part, N);
    k_scan_mid<<<1, 1024, 0, stream>>>(part, part_s, npart, gcnt, gptr, G, rowptr, N);
    k_scan_out<<<npart, 256, 0, stream>>>(ideg, part_s, rowptr, cursor, N);
    k_scatter<<<512, 256, 0, stream>>>(ei, E, Epad, cursor, eid_s, esrc_s, dst_s, ea_s);
    k_permute_ea<<<2048, 256, 0, stream>>>(ea, eid_s, ea_s, E);
    k_wprep<<<194, 256, 0, stream>>>(we1, we2, we3, wn1, wn2, wn3, w4,
                                     webf1, webf2, webf3, wnbf1, wnbf2, wnbf3, w4t);
    k_xprep<<<1250, 256, 0, stream>>>(x, x_bf, aggrA, N * 16);

    // ---- Layer 1 (D=64) ----
    k_edge_mfma<64><<<eblk64, 256, 0, stream>>>(
        x_bf, ea_s, esrc_s, dst_s, webf1, be1, aggrA, E);
    k_node_mfma<64, true><<<nblk64, 256, 0, stream>>>(aggrA, wnbf1, bnb1, g1, b1, rm1, rv1,
                                                      h_bf, aggrB, N);

    // ---- Layer 2 (D=256) ----
    k_edge_mfma<256><<<eblk256, 256, 0, stream>>>(
        h_bf, ea_s, esrc_s, dst_s, webf2, be2, aggrB, E);
    k_node_mfma<256, true><<<nblk64, 256, 0, stream>>>(aggrB, wnbf2, bnb2, g2, b2, rm2, rv2,
                                                       h_bf, aggrA, N);

    // ---- Layer 3 (D=256) ----
    k_edge_mfma<256><<<eblk256, 256, 0, stream>>>(
        h_bf, ea_s, esrc_s, dst_s, webf3, be3, aggrA, E);
    k_node_mfma<256, false><<<nblk64, 256, 0, stream>>>(aggrA, wnbf3, bnb3, g3, b3, rm3, rv3,
                                                        h_bf, (float*)nullptr, N);

    // ---- Fused pool + head ----
    k_pool_head<<<G, 256, 0, stream>>>(h_bf, gptr, w4t, b4, w5, b5, (float*)d_out);
}

// Round 13
// 261.833 us; speedup vs baseline: 4.3173x; 1.2711x over previous
//
#include <hip/hip_runtime.h>
#include <hip/hip_bf16.h>
#include <math.h>

// ---------------------------------------------------------------------------
// GINE model: 3x (GINEConv + BN + ReLU) -> global mean pool -> MLP -> sigmoid
// Round 13: edge flush = tile prefix + SCALAR segment walk (uniform ctz loop,
// compile-time (q,i) via switch, telescoping difference in-register) ->
// r9's atomic message count with r12's VALU. Fused scatter+ea-permute and
// wprep+xprep (2 fewer launches, no 40MB random gather).
// ---------------------------------------------------------------------------

typedef __attribute__((ext_vector_type(8))) short short8v;
typedef __attribute__((ext_vector_type(4))) float f32x4;
typedef __attribute__((ext_vector_type(4))) unsigned short us4;
typedef __attribute__((ext_vector_type(8))) unsigned short us8;

static __device__ __forceinline__ float bf2f(unsigned short u) {
    union { unsigned int u32; float f; } c; c.u32 = ((unsigned int)u) << 16; return c.f;
}
static __device__ __forceinline__ unsigned short f2bf(float f) {
    union { float f; unsigned int u; } c; c.f = f;
    unsigned int lsb = (c.u >> 16) & 1u;
    c.u += 0x7fffu + lsb;
    return (unsigned short)(c.u >> 16);
}

__global__ void k_zero_i(int* __restrict__ p, int n) {
    int i = blockIdx.x * blockDim.x + threadIdx.x;
    int st = gridDim.x * blockDim.x;
    for (; i < n; i += st) p[i] = 0;
}

// dst histogram (blocks 0..511) + batch histogram (blocks 512..639)
__global__ void k_hist2(const int* __restrict__ dst, int E,
                        const int* __restrict__ batch, int N,
                        int* __restrict__ ideg, int* __restrict__ gcnt) {
    int b = blockIdx.x;
    if (b < 512) {
        int i = b * 256 + threadIdx.x, st = 512 * 256;
        for (; i < E; i += st) atomicAdd(&ideg[dst[i]], 1);
    } else {
        int i = (b - 512) * 256 + threadIdx.x, st = 128 * 256;
        for (; i < N; i += st) atomicAdd(&gcnt[batch[i]], 1);
    }
}

// ---- multi-block scan: part -> mid -> out ----
__global__ __launch_bounds__(256) void k_scan_part(const int* __restrict__ in,
                                                   int* __restrict__ part, int n) {
    __shared__ int wtot[4];
    const int tid = threadIdx.x, lane = tid & 63, wv = tid >> 6;
    int i = blockIdx.x * 256 + tid;
    int s = (i < n) ? in[i] : 0;
#pragma unroll
    for (int off = 1; off < 64; off <<= 1) s += __shfl_xor(s, off);
    if (lane == 0) wtot[wv] = s;
    __syncthreads();
    if (tid == 0) part[blockIdx.x] = wtot[0] + wtot[1] + wtot[2] + wtot[3];
}

static __device__ void scan_block(const int* __restrict__ in, int* __restrict__ out,
                                  int n, int* wsum) {
    const int tid = threadIdx.x;
    const int lane = tid & 63, wv = tid >> 6;
    const int C = (n + 1023) >> 10;
    const int base = tid * C;
    int s = 0;
    for (int k = 0; k < C; ++k) {
        int i = base + k;
        if (i < n) s += in[i];
    }
    int incl = s;
#pragma unroll
    for (int off = 1; off < 64; off <<= 1) {
        int t = __shfl_up(incl, off);
        if (lane >= off) incl += t;
    }
    if (lane == 63) wsum[wv] = incl;
    __syncthreads();
    int woff = 0;
    for (int i2 = 0; i2 < wv; ++i2) woff += wsum[i2];
    int run = woff + incl - s;
    for (int k = 0; k < C; ++k) {
        int i = base + k;
        if (i < n) {
            out[i] = run;
            run += in[i];
        }
    }
    if (tid == 1023) out[n] = run;
    __syncthreads();
}

__global__ __launch_bounds__(1024) void k_scan_mid(
    const int* __restrict__ part, int* __restrict__ part_s, int npart,
    const int* __restrict__ gcnt, int* __restrict__ gptr, int G,
    int* __restrict__ rowptr, int N) {
    __shared__ int wsum[16];
    scan_block(part, part_s, npart, wsum);
    if (threadIdx.x == 0) rowptr[N] = part_s[npart];
    scan_block(gcnt, gptr, G, wsum);
}

__global__ __launch_bounds__(256) void k_scan_out(const int* __restrict__ in,
                                                  const int* __restrict__ part_s,
                                                  int* __restrict__ rowptr,
                                                  int* __restrict__ cursor, int n) {
    __shared__ int wtot[4];
    const int tid = threadIdx.x, lane = tid & 63, wv = tid >> 6;
    int i = blockIdx.x * 256 + tid;
    int v = (i < n) ? in[i] : 0;
    int s = v;
#pragma unroll
    for (int off = 1; off < 64; off <<= 1) {
        int t = __shfl_up(s, off);
        if (lane >= off) s += t;
    }
    if (lane == 63) wtot[wv] = s;
    __syncthreads();
    int woff = 0;
    for (int k = 0; k < wv; ++k) woff += wtot[k];
    int excl = part_s[blockIdx.x] + woff + s - v;
    if (i < n) { rowptr[i] = excl; cursor[i] = excl; }
}

// bucket edges by dst; convert+write ea row at pos directly (fused permute);
// pad tails: rows [E, Epad) fully; dst also [Epad, Epad+64)
__global__ void k_scatter(const int* __restrict__ ei, const float* __restrict__ ea,
                          int E, int Epad, int* __restrict__ cursor,
                          int* __restrict__ esrc_s, int* __restrict__ dst_s,
                          unsigned short* __restrict__ ea_s) {
    int i = blockIdx.x * blockDim.x + threadIdx.x;
    int st = gridDim.x * blockDim.x;
    for (int k = i; k < E; k += st) {
        int d = ei[E + k];
        int pos = atomicAdd(&cursor[d], 1);
        esrc_s[pos] = ei[k];
        dst_s[pos] = d;
        const float4* sp = (const float4*)(ea + (size_t)k * 32);
        unsigned short* dp = ea_s + (size_t)pos * 32;
#pragma unroll
        for (int h = 0; h < 4; ++h) {
            float4 a = sp[2 * h], b = sp[2 * h + 1];
            us8 o;
            o[0] = f2bf(a.x); o[1] = f2bf(a.y); o[2] = f2bf(a.z); o[3] = f2bf(a.w);
            o[4] = f2bf(b.x); o[5] = f2bf(b.y); o[6] = f2bf(b.z); o[7] = f2bf(b.w);
            *(us8*)(dp + h * 8) = o;
        }
    }
    if (i < Epad + 64 - E) {
        dst_s[E + i] = -1;
        if (i < Epad - E) {
            esrc_s[E + i] = 0;
            us4 z = {0, 0, 0, 0};
            us4* p = (us4*)(ea_s + (size_t)(E + i) * 32);
#pragma unroll
            for (int q = 0; q < 8; ++q) p[q] = z;
        }
    }
}

// fused weight prep (bf16 casts + permuted w4 transpose) + x prep
__global__ void k_wxprep(const float* __restrict__ we1, const float* __restrict__ we2,
                         const float* __restrict__ we3, const float* __restrict__ wn1,
                         const float* __restrict__ wn2, const float* __restrict__ wn3,
                         const float* __restrict__ w4, const float* __restrict__ x,
                         unsigned short* __restrict__ webf1, unsigned short* __restrict__ webf2,
                         unsigned short* __restrict__ webf3, unsigned short* __restrict__ wnbf1,
                         unsigned short* __restrict__ wnbf2, unsigned short* __restrict__ wnbf3,
                         float* __restrict__ w4t, unsigned short* __restrict__ x_bf,
                         float* __restrict__ aggrA, int n16) {
    int idx = blockIdx.x * blockDim.x + threadIdx.x;
    if (idx >= 49664) {
        int i = idx - 49664;
        if (i < n16) {
            int n = i >> 4, j = i & 15;
            float4 t = *(const float4*)(x + (size_t)n * 64 + j * 4);
            ((float4*)aggrA)[i] = t;
            us4 o;
            o.x = f2bf(x[(size_t)n * 64 + j]);
            o.y = f2bf(x[(size_t)n * 64 + 16 + j]);
            o.z = f2bf(x[(size_t)n * 64 + 32 + j]);
            o.w = f2bf(x[(size_t)n * 64 + 48 + j]);
            *(us4*)(x_bf + (size_t)n * 64 + j * 4) = o;
        }
        return;
    }
    const float* s; unsigned short* d; int rel;
    if (idx < 512)        { s = we1; d = webf1; rel = idx; }
    else if (idx < 2560)  { s = we2; d = webf2; rel = idx - 512; }
    else if (idx < 4608)  { s = we3; d = webf3; rel = idx - 2560; }
    else if (idx < 8704)  { s = wn1; d = wnbf1; rel = idx - 4608; }
    else if (idx < 25088) { s = wn2; d = wnbf2; rel = idx - 8704; }
    else if (idx < 41472) { s = wn3; d = wnbf3; rel = idx - 25088; }
    else {
        int rel2 = idx - 41472;
        int k = rel2 >> 5;
        int j0 = (rel2 & 31) * 4;
        int ck = (k & 0xC0) | (((k & 3) * 16) + ((k & 63) >> 2));
        float4 o;
        o.x = w4[(j0 + 0) * 256 + ck]; o.y = w4[(j0 + 1) * 256 + ck];
        o.z = w4[(j0 + 2) * 256 + ck]; o.w = w4[(j0 + 3) * 256 + ck];
        *(float4*)(w4t + k * 128 + j0) = o;
        return;
    }
    float4 t = ((const float4*)s)[rel];
    us4 o; o.x = f2bf(t.x); o.y = f2bf(t.y); o.z = f2bf(t.z); o.w = f2bf(t.w);
    ((us4*)d)[rel] = o;
}

// ---------------------------------------------------------------------------
// Edge kernel. Permuted-h 8B gathers; tile-wide inclusive prefix; flush via
// SCALAR walk of the uniform segment-end mask: per segment, uniform (q,i)
// switch + 4 shfl fetch P[end], emit (curP - prevP) with 4 atomics from the
// 16 lhi==0 lanes. Message count = nseg (r9 level), VALU ~= prefix only.
// aggr must be pre-initialized with the self term (f32, natural layout).
// ---------------------------------------------------------------------------
template<int D>
__global__ __launch_bounds__(256) void k_edge_mfma(
    const unsigned short* __restrict__ hbf,   // [N][D] bf16, PERMUTED layout
    const unsigned short* __restrict__ ea_s,  // [Epad][32] bf16, CSR order
    const int* __restrict__ esrc_s,           // [Epad]
    const int* __restrict__ dst_s,            // [Epad+64], tail = -1
    const unsigned short* __restrict__ webf,  // [D][32] bf16, natural rows
    const float* __restrict__ be,             // [D]
    float* __restrict__ aggr,                 // [N][D] f32, natural layout
    int E)
{
    const int tid = threadIdx.x;
    const int lane = tid & 63;
    const int w = tid >> 6;
    const int l15 = lane & 15;
    const int lhi = lane >> 4;

    const int wavetile = (D == 256) ? (int)blockIdx.x : ((int)blockIdx.x * 4 + w);
    const int colbase  = (D == 256) ? (w * 64) : 0;
    const int e0 = wavetile * 64;
    if (e0 >= E) return;

    const int dstreg = dst_s[e0 + lane];      // lane = row

    int4 src4[4];
#pragma unroll
    for (int q = 0; q < 4; ++q)
        src4[q] = *(const int4*)(esrc_s + e0 + q * 16 + lhi * 4);

    short8v afr[4];
#pragma unroll
    for (int q = 0; q < 4; ++q)
        afr[q] = *(const short8v*)(ea_s + (size_t)(e0 + q * 16 + l15) * 32 + lhi * 8);

    short8v bfr[4]; float bias[4];
#pragma unroll
    for (int t = 0; t < 4; ++t) {
        int c = colbase + t * 16 + l15;
        bfr[t] = *(const short8v*)(webf + (size_t)c * 32 + lhi * 8);
        bias[t] = be[c];
    }

    // permuted h-gather: one us4 per fragment row -> channels {t*16+l15}
    us4 hv[4][4];
#pragma unroll
    for (int q = 0; q < 4; ++q) {
        const int sr[4] = {src4[q].x, src4[q].y, src4[q].z, src4[q].w};
#pragma unroll
        for (int i = 0; i < 4; ++i)
            hv[q][i] = *(const us4*)(hbf + (size_t)sr[i] * D + colbase + l15 * 4);
    }

    f32x4 acc[4][4];
#pragma unroll
    for (int q = 0; q < 4; ++q)
#pragma unroll
        for (int t = 0; t < 4; ++t) {
            f32x4 ci; ci[0] = bias[t]; ci[1] = bias[t]; ci[2] = bias[t]; ci[3] = bias[t];
            acc[q][t] = __builtin_amdgcn_mfma_f32_16x16x32_bf16(afr[q], bfr[t], ci, 0, 0, 0);
        }

    // m = relu(el + h_src)
#pragma unroll
    for (int q = 0; q < 4; ++q)
#pragma unroll
        for (int i = 0; i < 4; ++i) {
            us4 h4 = hv[q][i];
#pragma unroll
            for (int t = 0; t < 4; ++t)
                acc[q][t][i] = fmaxf(acc[q][t][i] + bf2f(h4[t]), 0.0f);
        }

    // ---- tile-wide inclusive prefix (in place on acc) ----
    float carry[4] = {0.0f, 0.0f, 0.0f, 0.0f};
#pragma unroll
    for (int q = 0; q < 4; ++q)
#pragma unroll
        for (int t = 0; t < 4; ++t) {
            acc[q][t][1] += acc[q][t][0];
            acc[q][t][2] += acc[q][t][1];
            acc[q][t][3] += acc[q][t][2];
            float g = acc[q][t][3];
            float g1 = __shfl_up(g, 16);
            if (lhi >= 1) g += g1;
            float g2 = __shfl_up(g, 32);
            if (lhi >= 2) g += g2;
            float tqv = __shfl(g, 48 + l15);        // subtile total (lhi=3 incl)
            float excl = g - acc[q][t][3] + carry[t];
            acc[q][t][0] += excl; acc[q][t][1] += excl;
            acc[q][t][2] += excl; acc[q][t][3] += excl;
            carry[t] += tqv;
        }

    // ---- segment-end mask (row = lane; forced end at row 63) ----
    int dnext = __shfl_down(dstreg, 1);
    bool endf = (lane == 63) || (dstreg != dnext);
    unsigned long long mask = __ballot(endf);

    // ---- scalar segment walk with telescoping difference ----
    float prevP[4] = {0.0f, 0.0f, 0.0f, 0.0f};
    while (mask) {
        int r = __builtin_amdgcn_readfirstlane((int)__builtin_ctzll(mask));
        mask &= mask - 1;
        int dseg = __shfl(dstreg, r);
        int sl = ((r >> 2) & 3) * 16 + l15;     // source lane holding row r
        float curP[4];
        switch (((r >> 4) << 2) | (r & 3)) {
#define CASE_QI(Q, I) \
            case ((Q) * 4 + (I)): \
                curP[0] = __shfl(acc[Q][0][I], sl); curP[1] = __shfl(acc[Q][1][I], sl); \
                curP[2] = __shfl(acc[Q][2][I], sl); curP[3] = __shfl(acc[Q][3][I], sl); \
                break;
            CASE_QI(0,0) CASE_QI(0,1) CASE_QI(0,2) CASE_QI(0,3)
            CASE_QI(1,0) CASE_QI(1,1) CASE_QI(1,2) CASE_QI(1,3)
            CASE_QI(2,0) CASE_QI(2,1) CASE_QI(2,2) CASE_QI(2,3)
            CASE_QI(3,0) CASE_QI(3,1) CASE_QI(3,2) CASE_QI(3,3)
#undef CASE_QI
        }
        if (dseg >= 0 && lhi == 0) {
            float* base = aggr + (size_t)dseg * D + colbase + l15;
#pragma unroll
            for (int t = 0; t < 4; ++t)
                atomicAdd(base + t * 16, curP[t] - prevP[t]);
        }
#pragma unroll
        for (int t = 0; t < 4; ++t) prevP[t] = curP[t];
    }
}

// ---------------------------------------------------------------------------
// MFMA node GEMM + BN + ReLU. Natural aggr in/out; h_bf stored PERMUTED via
// two 16B stores per row-fragment.
// ---------------------------------------------------------------------------
template<int K, bool AW>
__global__ __launch_bounds__(256) void k_node_mfma(
    const float* __restrict__ A, const unsigned short* __restrict__ wnbf,
    const float* __restrict__ bnb, const float* __restrict__ g,
    const float* __restrict__ b, const float* __restrict__ rm,
    const float* __restrict__ rv, unsigned short* __restrict__ out,
    float* __restrict__ aggr_out, int N)
{
    const int tid = threadIdx.x;
    const int lane = tid & 63;
    const int w = tid >> 6;
    const int l15 = lane & 15;
    const int lhi = lane >> 4;
    const int row0 = blockIdx.x * 64;
    const int ncol0 = w * 64;

    f32x4 scale[4], shift[4];
    f32x4 acc[4][4];
#pragma unroll
    for (int q = 0; q < 4; ++q) {
        int n0 = ncol0 + q * 16 + lhi * 4;
        float4 gg = *(const float4*)(g + n0);
        float4 rvv = *(const float4*)(rv + n0);
        float4 bb = *(const float4*)(b + n0);
        float4 rmm = *(const float4*)(rm + n0);
        float4 bn = *(const float4*)(bnb + n0);
        f32x4 sc, sh, ci;
        sc[0] = gg.x * rsqrtf(rvv.x + 1e-5f);
        sc[1] = gg.y * rsqrtf(rvv.y + 1e-5f);
        sc[2] = gg.z * rsqrtf(rvv.z + 1e-5f);
        sc[3] = gg.w * rsqrtf(rvv.w + 1e-5f);
        sh[0] = bb.x - rmm.x * sc[0];
        sh[1] = bb.y - rmm.y * sc[1];
        sh[2] = bb.z - rmm.z * sc[2];
        sh[3] = bb.w - rmm.w * sc[3];
        ci[0] = bn.x; ci[1] = bn.y; ci[2] = bn.z; ci[3] = bn.w;
        scale[q] = sc; shift[q] = sh;
#pragma unroll
        for (int r = 0; r < 4; ++r) acc[q][r] = ci;
    }

    for (int k0 = 0; k0 < K; k0 += 32) {
        short8v wfr[4];
#pragma unroll
        for (int q = 0; q < 4; ++q)
            wfr[q] = *(const short8v*)(wnbf + (size_t)(ncol0 + q * 16 + l15) * K + k0 + lhi * 8);
        short8v afr[4];
#pragma unroll
        for (int r = 0; r < 4; ++r) {
            const float* ap = A + (size_t)(row0 + r * 16 + l15) * K + k0 + lhi * 8;
            float4 a0 = ((const float4*)ap)[0];
            float4 a1 = ((const float4*)ap)[1];
            short8v t;
            t[0] = (short)f2bf(a0.x); t[1] = (short)f2bf(a0.y);
            t[2] = (short)f2bf(a0.z); t[3] = (short)f2bf(a0.w);
            t[4] = (short)f2bf(a1.x); t[5] = (short)f2bf(a1.y);
            t[6] = (short)f2bf(a1.z); t[7] = (short)f2bf(a1.w);
            afr[r] = t;
        }
#pragma unroll
        for (int q = 0; q < 4; ++q)
#pragma unroll
            for (int r = 0; r < 4; ++r)
                acc[q][r] = __builtin_amdgcn_mfma_f32_16x16x32_bf16(wfr[q], afr[r], acc[q][r], 0, 0, 0);
    }

#pragma unroll
    for (int r = 0; r < 4; ++r) {
        int m = row0 + r * 16 + l15;
        if (m < N) {
            f32x4 o4[4];
#pragma unroll
            for (int q = 0; q < 4; ++q) {
                int n0 = ncol0 + q * 16 + lhi * 4;
                f32x4 v = acc[q][r];
                f32x4 o;
#pragma unroll
                for (int i = 0; i < 4; ++i)
                    o[i] = fmaxf(v[i] * scale[q][i] + shift[q][i], 0.0f);
                o4[q] = o;
                if (AW) *(f32x4*)(aggr_out + (size_t)m * 256 + n0) = o;
            }
            us8 lo, hi;
#pragma unroll
            for (int q = 0; q < 4; ++q)
#pragma unroll
                for (int i = 0; i < 4; ++i) {
                    int p = i * 4 + q;
                    unsigned short v = f2bf(o4[q][i]);
                    if (p < 8) lo[p] = v; else hi[p - 8] = v;
                }
            *(us8*)(out + (size_t)m * 256 + ncol0 + lhi * 16) = lo;
            *(us8*)(out + (size_t)m * 256 + ncol0 + lhi * 16 + 8) = hi;
        }
    }
}

// Fused global-mean-pool + MLP head (h in PERMUTED bf16; w4t pre-permuted).
__global__ __launch_bounds__(256) void k_pool_head(
    const unsigned short* __restrict__ h, const int* __restrict__ gptr,
    const float* __restrict__ w4t, const float* __restrict__ b4,
    const float* __restrict__ w5, const float* __restrict__ b5,
    float* __restrict__ out)
{
    __shared__ float pl[256];
    __shared__ float zs[128];
    const int g = blockIdx.x;
    const int tid = threadIdx.x;
    int beg = gptr[g], end = gptr[g + 1];
    float acc = 0.0f;
    for (int r = beg; r < end; ++r) acc += bf2f(h[(size_t)r * 256 + tid]);
    float cnt = (float)(end - beg);
    pl[tid] = acc / fmaxf(cnt, 1.0f);
    __syncthreads();
    if (tid < 128) {
        float a = b4[tid];
        for (int k = 0; k < 256; ++k) a += pl[k] * w4t[k * 128 + tid];
        zs[tid] = fmaxf(a, 0.0f);
    }
    __syncthreads();
    if (tid < 64) {
        float v = zs[tid] * w5[tid] + zs[tid + 64] * w5[tid + 64];
#pragma unroll
        for (int off = 32; off > 0; off >>= 1) v += __shfl_down(v, off);
        if (tid == 0) out[g] = 1.0f / (1.0f + expf(-(v + b5[0])));
    }
}

extern "C" void kernel_launch(void* const* d_in, const int* in_sizes, int n_in,
                              void* d_out, int out_size, void* d_ws, size_t ws_size,
                              hipStream_t stream)
{
    const float* x    = (const float*)d_in[0];
    const int*   ei   = (const int*)d_in[1];
    const float* ea   = (const float*)d_in[2];
    const int*   batch= (const int*)d_in[3];
    const float* we1  = (const float*)d_in[4];
    const float* be1  = (const float*)d_in[5];
    const float* wn1  = (const float*)d_in[6];
    const float* bnb1 = (const float*)d_in[7];
    const float* we2  = (const float*)d_in[8];
    const float* be2  = (const float*)d_in[9];
    const float* wn2  = (const float*)d_in[10];
    const float* bnb2 = (const float*)d_in[11];
    const float* we3  = (const float*)d_in[12];
    const float* be3  = (const float*)d_in[13];
    const float* wn3  = (const float*)d_in[14];
    const float* bnb3 = (const float*)d_in[15];
    const float* g1 = (const float*)d_in[16];
    const float* b1 = (const float*)d_in[17];
    const float* rm1= (const float*)d_in[18];
    const float* rv1= (const float*)d_in[19];
    const float* g2 = (const float*)d_in[20];
    const float* b2 = (const float*)d_in[21];
    const float* rm2= (const float*)d_in[22];
    const float* rv2= (const float*)d_in[23];
    const float* g3 = (const float*)d_in[24];
    const float* b3 = (const float*)d_in[25];
    const float* rm3= (const float*)d_in[26];
    const float* rv3= (const float*)d_in[27];
    const float* w4 = (const float*)d_in[28];
    const float* b4 = (const float*)d_in[29];
    const float* w5 = (const float*)d_in[30];
    const float* b5 = (const float*)d_in[31];

    const int N = in_sizes[0] / 64;
    const int E = in_sizes[1] / 2;
    const int G = out_size;
    const int Epad = (E + 63) & ~63;
    const int npart = (N + 255) / 256;

    // ---- workspace layout ----
    float* ws    = (float*)d_ws;
    float* aggrA = ws;                                  // N*256 f32
    float* aggrB = aggrA + (size_t)N * 256;             // N*256 f32
    float* w4t   = aggrB + (size_t)N * 256;             // 256*128
    unsigned short* ea_s  = (unsigned short*)(w4t + 256 * 128);   // Epad*32 bf16
    unsigned short* x_bf  = ea_s + (size_t)Epad * 32;   // N*64 bf16 (permuted)
    unsigned short* h_bf  = x_bf + (size_t)N * 64;      // N*256 bf16 (permuted)
    unsigned short* webf1 = h_bf + (size_t)N * 256;     // 64*32 bf16
    unsigned short* webf2 = webf1 + 64 * 32;            // 256*32
    unsigned short* webf3 = webf2 + 256 * 32;           // 256*32
    unsigned short* wnbf1 = webf3 + 256 * 32;           // 256*64 bf16
    unsigned short* wnbf2 = wnbf1 + 256 * 64;           // 256*256
    unsigned short* wnbf3 = wnbf2 + 256 * 256;          // 256*256
    int* iws    = (int*)(wnbf3 + 256 * 256);
    int* ideg   = iws;                                  // N   (gcnt adjacent!)
    int* gcnt   = ideg + N;                             // G
    int* rowptr = gcnt + G;                             // N+16
    int* gptr   = rowptr + N + 16;                      // G+16
    int* cursor = gptr + G + 16;                        // N
    int* esrc_s = cursor + N;                           // Epad
    int* dst_s  = esrc_s + Epad;                        // Epad+64 (tail -1)
    int* part   = dst_s + Epad + 64;                    // npart
    int* part_s = part + npart;                         // npart+1

    const int nblk64  = (N + 63) / 64;
    const int eblk256 = (E + 63) / 64;
    const int eblk64  = (E + 255) / 256;

    // ---- fused preprocessing ----
    k_zero_i<<<64, 256, 0, stream>>>(ideg, N + G);
    k_hist2<<<640, 256, 0, stream>>>(ei + E, E, batch, N, ideg, gcnt);
    k_scan_part<<<npart, 256, 0, stream>>>(ideg, part, N);
    k_scan_mid<<<1, 1024, 0, stream>>>(part, part_s, npart, gcnt, gptr, G, rowptr, N);
    k_scan_out<<<npart, 256, 0, stream>>>(ideg, part_s, rowptr, cursor, N);
    k_scatter<<<512, 256, 0, stream>>>(ei, ea, E, Epad, cursor, esrc_s, dst_s, ea_s);
    k_wxprep<<<(49664 + 320000 + 255) / 256, 256, 0, stream>>>(
        we1, we2, we3, wn1, wn2, wn3, w4, x,
        webf1, webf2, webf3, wnbf1, wnbf2, wnbf3, w4t, x_bf, aggrA, N * 16);

    // ---- Layer 1 (D=64) ----
    k_edge_mfma<64><<<eblk64, 256, 0, stream>>>(
        x_bf, ea_s, esrc_s, dst_s, webf1, be1, aggrA, E);
    k_node_mfma<64, true><<<nblk64, 256, 0, stream>>>(aggrA, wnbf1, bnb1, g1, b1, rm1, rv1,
                                                      h_bf, aggrB, N);

    // ---- Layer 2 (D=256) ----
    k_edge_mfma<256><<<eblk256, 256, 0, stream>>>(
        h_bf, ea_s, esrc_s, dst_s, webf2, be2, aggrB, E);
    k_node_mfma<256, true><<<nblk64, 256, 0, stream>>>(aggrB, wnbf2, bnb2, g2, b2, rm2, rv2,
                                                       h_bf, aggrA, N);

    // ---- Layer 3 (D=256) ----
    k_edge_mfma<256><<<eblk256, 256, 0, stream>>>(
        h_bf, ea_s, esrc_s, dst_s, webf3, be3, aggrA, E);
    k_node_mfma<256, false><<<nblk64, 256, 0, stream>>>(aggrA, wnbf3, bnb3, g3, b3, rm3, rv3,
                                                        h_bf, (float*)nullptr, N);

    // ---- Fused pool + head ----
    k_pool_head<<<G, 256, 0, stream>>>(h_bf, gptr, w4t, b4, w5, b5, (float*)d_out);
}